// Round 5
// baseline (766.126 us; speedup 1.0000x reference)
//
#include <hip/hip_runtime.h>
#include <hip/hip_fp16.h>

#define NN 100000
#define NE 1600000
#define NG 512
#define OUTS 8128
#define NBUK 3125   // 32 nodes per bucket, exact: 3125*32 = 100000

typedef short bf16x8 __attribute__((ext_vector_type(8)));
typedef float f32x4 __attribute__((ext_vector_type(4)));

__device__ __forceinline__ unsigned pack_bf16x2(float a, float b) {
    unsigned ua = __float_as_uint(a);
    unsigned ub = __float_as_uint(b);
    ua = (ua + 0x7fffu + ((ua >> 16) & 1u)) >> 16;
    ub = (ub + 0x7fffu + ((ub >> 16) & 1u)) >> 16;
    return ua | (ub << 16);
}
__device__ __forceinline__ unsigned short f2bf(float f) {
    unsigned u = __float_as_uint(f);
    u = (u + 0x7fffu + ((u >> 16) & 1u)) >> 16;
    return (unsigned short)u;
}
__device__ __forceinline__ float bf16lo(unsigned u) { return __uint_as_float(u << 16); }
__device__ __forceinline__ float bf16hi(unsigned u) { return __uint_as_float(u & 0xffff0000u); }

// e4m3 encode for f >= 0 (relu'd), via f16: e4m3(v) bits == f16(v/256) rounded 10->3 mantissa bits
__device__ __forceinline__ unsigned f2fp8(float f) {
    unsigned h = (unsigned)__half_as_ushort(__float2half(f * 0.00390625f));
    return (h + 0x3Fu + ((h >> 7) & 1u)) >> 7;
}
// decode: value/256 (fold x256 into final scale)
__device__ __forceinline__ float fp8tof(unsigned b) {
    unsigned short u = (unsigned short)(((b & 0x80u) << 8) | ((b & 0x7Fu) << 7));
    return __half2float(__ushort_as_half(u));
}

// ---- int degree ----
__global__ __launch_bounds__(256) void k_deg(const int* __restrict__ dst, int* __restrict__ cnt) {
    int e = blockIdx.x * 256 + threadIdx.x;
    if (e < NE) atomicAdd(&cnt[dst[e]], 1);
}

__global__ __launch_bounds__(256) void k_dinv(const int* __restrict__ cnt, float* __restrict__ dinv) {
    int i = blockIdx.x * 256 + threadIdx.x;
    if (i < NN) dinv[i] = rsqrtf((float)cnt[i] + 1.0f);
}

// ---- hierarchical exclusive scan ----
__global__ __launch_bounds__(256) void k_scanA(const int* __restrict__ cnt, int* __restrict__ pre,
                                               int* __restrict__ bsum) {
    __shared__ int lds[256];
    int base = blockIdx.x * 1024 + threadIdx.x * 4;
    int v0 = 0, v1 = 0, v2 = 0, v3 = 0;
    if (base + 3 < NN) {
        int4 c = *(const int4*)&cnt[base];
        v0 = c.x; v1 = c.y; v2 = c.z; v3 = c.w;
    } else {
        if (base + 0 < NN) v0 = cnt[base + 0];
        if (base + 1 < NN) v1 = cnt[base + 1];
        if (base + 2 < NN) v2 = cnt[base + 2];
    }
    int s = v0 + v1 + v2 + v3;
    lds[threadIdx.x] = s;
    __syncthreads();
    for (int off = 1; off < 256; off <<= 1) {
        int t = (threadIdx.x >= off) ? lds[threadIdx.x - off] : 0;
        __syncthreads();
        lds[threadIdx.x] += t;
        __syncthreads();
    }
    int excl = lds[threadIdx.x] - s;
    if (threadIdx.x == 255) bsum[blockIdx.x] = lds[255];
    if (base < NN) {
        int p0 = excl, p1 = p0 + v0, p2 = p1 + v1, p3 = p2 + v2;
        if (base + 3 < NN) { int4 o = {p0, p1, p2, p3}; *(int4*)&pre[base] = o; }
        else {
            pre[base] = p0;
            if (base + 1 < NN) pre[base + 1] = p1;
            if (base + 2 < NN) pre[base + 2] = p2;
        }
    }
}

__global__ void k_scanB(const int* __restrict__ bsum, int* __restrict__ boff, int nb) {
    __shared__ int lds[128];
    int v = (threadIdx.x < nb) ? bsum[threadIdx.x] : 0;
    lds[threadIdx.x] = v;
    __syncthreads();
    for (int off = 1; off < 128; off <<= 1) {
        int t = (threadIdx.x >= off) ? lds[threadIdx.x - off] : 0;
        __syncthreads();
        lds[threadIdx.x] += t;
        __syncthreads();
    }
    if (threadIdx.x < nb) boff[threadIdx.x] = lds[threadIdx.x] - v;
}

__global__ __launch_bounds__(256) void k_scanC(int* __restrict__ pre, const int* __restrict__ boff) {
    int i = blockIdx.x * 256 + threadIdx.x;
    if (i < NN) pre[i] += boff[i >> 10];
}

// ---- bucket bases ----
__global__ __launch_bounds__(256) void k_bbase(const int* __restrict__ rowptr, int* __restrict__ bbase) {
    int b = blockIdx.x * 256 + threadIdx.x;
    if (b < NBUK) bbase[b] = rowptr[b << 5];
}

// ---- pass B: scatter edges into dense per-bucket regions ----
__global__ __launch_bounds__(256) void k_bfill(const int* __restrict__ src, const int* __restrict__ dst,
        const int* __restrict__ bbase, int* __restrict__ bcur, int* __restrict__ tmp) {
    int e = blockIdx.x * 256 + threadIdx.x;
    if (e >= NE) return;
    int d = dst[e];
    int b = d >> 5;
    int pos = atomicAdd(&bcur[b], 1);
    tmp[bbase[b] + pos] = (src[e] << 5) | (d & 31);
}

// ---- pass C: per-bucket counting sort into colidx (dense 2KB region/block) ----
__global__ __launch_bounds__(128) void k_csort(const int* __restrict__ bbase,
        const int* __restrict__ rowptr, const int* __restrict__ tmp, int* __restrict__ colidx) {
    __shared__ int rbase[32], lcur[32];
    int b = blockIdx.x, t = threadIdx.x;
    int n0 = b << 5;
    if (t < 32) {
        rbase[t] = rowptr[n0 + t];
        lcur[t] = 0;
    }
    __syncthreads();
    int beg = bbase[b];
    int end = (b + 1 < NBUK) ? bbase[b + 1] : NE;
    for (int i = beg + t; i < end; i += 128) {
        int v = tmp[i];
        int dl = v & 31;
        int pos = atomicAdd(&lcur[dl], 1);
        colidx[rbase[dl] + pos] = v >> 5;
    }
}

// ---- segment ends from sorted batch ----
__global__ __launch_bounds__(256) void k_segend(const int* __restrict__ batch, int* __restrict__ seg_end) {
    int i = blockIdx.x * 256 + threadIdx.x;
    if (i >= NN) return;
    int b = batch[i];
    int bn = (i == NN - 1) ? NG : batch[i + 1];
    for (int g = b; g < bn; ++g) seg_end[g] = i + 1;
    if (i == 0) {
        for (int g = 0; g < b; ++g) seg_end[g] = 0;
    }
}

// ---- W[K][128] fp32 -> WT[128][K] bf16 ----
template<int K>
__global__ __launch_bounds__(256) void k_wt(const float* __restrict__ W, unsigned short* __restrict__ wt) {
    int e = blockIdx.x * 256 + threadIdx.x;
    int n = e / K, k = e - n * K;
    wt[e] = f2bf(W[k * 128 + n]);
}

// ---- u1 = bf16(x * dinv[row]), 64ch ----
__global__ __launch_bounds__(256) void k_scale_x(const float* __restrict__ x,
        const float* __restrict__ dinv, unsigned* __restrict__ u1) {
    int i = blockIdx.x * 256 + threadIdx.x;   // < NN*32
    int row = i >> 5, c = i & 31;
    float2 v = *(const float2*)&x[(long)row * 64 + c * 2];
    float d = dinv[row];
    u1[i] = pack_bf16x2(v.x * d, v.y * d);
}

// ---- gather1: s1 = bf16(dinv_n * (u1[n] + sum u1[src])), 64ch bf16; 32 lanes/node ----
__global__ __launch_bounds__(256) void k_gather1(const int* __restrict__ rowptr,
        const int* __restrict__ cnti, const int* __restrict__ colidx,
        const unsigned* __restrict__ u, const float* __restrict__ dinv,
        unsigned* __restrict__ s1) {
    int node = blockIdx.x * 8 + (threadIdx.x >> 5);
    int lane = threadIdx.x & 31;
    unsigned uu = u[node * 32 + lane];
    float a0 = bf16lo(uu), a1 = bf16hi(uu);
    float b0 = 0.f, b1 = 0.f, c0 = 0.f, c1 = 0.f;
    int n = cnti[node];
    const int* ci = colidx + rowptr[node];
    int j = 0;
    for (; j + 2 <= n; j += 2) {
        unsigned u0 = u[ci[j] * 32 + lane];
        unsigned u1v = u[ci[j + 1] * 32 + lane];
        a0 += bf16lo(u0); a1 += bf16hi(u0);
        b0 += bf16lo(u1v); b1 += bf16hi(u1v);
    }
    if (j < n) {
        unsigned u0 = u[ci[j] * 32 + lane];
        a0 += bf16lo(u0); a1 += bf16hi(u0);
    }
    a0 += b0 + c0; a1 += b1 + c1;
    float d = dinv[node];
    s1[node * 32 + lane] = pack_bf16x2(a0 * d, a1 * d);
}

// ---- gather2: s2 = bf16(16*dinv_n * (q[n] + sum q[src])), q = fp8/256, 128ch; 32 lanes x 4ch ----
__global__ __launch_bounds__(256) void k_gather2(const int* __restrict__ rowptr,
        const int* __restrict__ cnti, const int* __restrict__ colidx,
        const unsigned* __restrict__ u, const float* __restrict__ dinv,
        unsigned* __restrict__ s2) {
    int node = blockIdx.x * 8 + (threadIdx.x >> 5);
    int lane = threadIdx.x & 31;
    unsigned uu = u[node * 32 + lane];
    float a0 = fp8tof(uu & 255), a1 = fp8tof((uu >> 8) & 255);
    float a2 = fp8tof((uu >> 16) & 255), a3 = fp8tof(uu >> 24);
    float b0 = 0.f, b1 = 0.f, b2 = 0.f, b3 = 0.f;
    int n = cnti[node];
    const int* ci = colidx + rowptr[node];
    int j = 0;
    for (; j + 2 <= n; j += 2) {
        unsigned v0 = u[ci[j] * 32 + lane];
        unsigned v1 = u[ci[j + 1] * 32 + lane];
        a0 += fp8tof(v0 & 255); a1 += fp8tof((v0 >> 8) & 255);
        a2 += fp8tof((v0 >> 16) & 255); a3 += fp8tof(v0 >> 24);
        b0 += fp8tof(v1 & 255); b1 += fp8tof((v1 >> 8) & 255);
        b2 += fp8tof((v1 >> 16) & 255); b3 += fp8tof(v1 >> 24);
    }
    if (j < n) {
        unsigned v0 = u[ci[j] * 32 + lane];
        a0 += fp8tof(v0 & 255); a1 += fp8tof((v0 >> 8) & 255);
        a2 += fp8tof((v0 >> 16) & 255); a3 += fp8tof(v0 >> 24);
    }
    a0 += b0; a1 += b1; a2 += b2; a3 += b3;
    float d = dinv[node] * 16.0f;   // * 256 (decode) / 16 (encode scale)
    uint2 o;
    o.x = pack_bf16x2(a0 * d, a1 * d);
    o.y = pack_bf16x2(a2 * d, a3 * d);
    *(uint2*)&s2[node * 64 + lane * 2] = o;
}

// ---- MFMA GEMM: h = relu(A@W + bias); EPI 0: out u2=fp8(16*dinv*h); EPI 1: out h bf16 ----
template<int K, int EPI>
__global__ __launch_bounds__(256) void k_gemm_mfma(const unsigned short* __restrict__ Ab,
        const unsigned short* __restrict__ wt, const float* __restrict__ dinv,
        const float* __restrict__ bias, void* __restrict__ outp) {
    constexpr int KS = K / 32;
    constexpr int SLOTS = K / 8;
    __shared__ __align__(16) unsigned short wlds[128 * K];
    char* lb = (char*)wlds;
    for (int c = threadIdx.x; c < 128 * SLOTS; c += 256) {
        int n = c / SLOTS, s = c - n * SLOTS;
        *(uint4*)(lb + n * (2 * K) + ((s ^ (n & 7)) << 4)) = *(const uint4*)(wt + c * 8);
    }
    __syncthreads();
    int lane = threadIdx.x & 63;
    int w = threadIdx.x >> 6;
    int r0 = blockIdx.x * 64 + w * 16;
    int arow = r0 + (lane & 15);
    if (arow >= NN) arow = NN - 1;
    bf16x8 af[KS];
    #pragma unroll
    for (int ks = 0; ks < KS; ++ks)
        af[ks] = *(const bf16x8*)&Ab[(long)arow * K + ks * 32 + (lane >> 4) * 8];
    f32x4 acc[8];
    #pragma unroll
    for (int t = 0; t < 8; ++t) acc[t] = (f32x4){0.f, 0.f, 0.f, 0.f};
    #pragma unroll
    for (int ks = 0; ks < KS; ++ks) {
        #pragma unroll
        for (int t = 0; t < 8; ++t) {
            int n = t * 16 + (lane & 15);
            int slot = ks * 4 + (lane >> 4);
            bf16x8 bf = *(const bf16x8*)(lb + n * (2 * K) + ((slot ^ (n & 7)) << 4));
            acc[t] = __builtin_amdgcn_mfma_f32_16x16x32_bf16(af[ks], bf, acc[t], 0, 0, 0);
        }
    }
    float bv[8];
    #pragma unroll
    for (int t = 0; t < 8; ++t) bv[t] = bias[t * 16 + (lane & 15)];
    #pragma unroll
    for (int r = 0; r < 4; ++r) {
        long row = r0 + (lane >> 4) * 4 + r;
        if (row >= NN) continue;
        float d = dinv[row];
        #pragma unroll
        for (int t = 0; t < 8; ++t) {
            float val = fmaxf(acc[t][r] + bv[t], 0.f);
            int col = t * 16 + (lane & 15);
            if (EPI == 0)
                ((unsigned char*)outp)[row * 128 + col] = (unsigned char)f2fp8(val * (16.0f * d));
            else
                ((unsigned short*)outp)[row * 128 + col] = f2bf(val);
        }
    }
}

// ---- segmented mean pool over bf16 h2 ----
__global__ __launch_bounds__(64) void k_poolmean(const unsigned* __restrict__ h,
        const int* __restrict__ seg_end, float* __restrict__ hg) {
    int g = blockIdx.x, t = threadIdx.x;
    int s = (g == 0) ? 0 : seg_end[g - 1];
    int e = seg_end[g];
    float a0 = 0.f, a1 = 0.f, b0 = 0.f, b1 = 0.f;
    int i = s;
    for (; i + 2 <= e; i += 2) {
        unsigned u0 = h[(long)i * 64 + t];
        unsigned u1 = h[(long)(i + 1) * 64 + t];
        a0 += bf16lo(u0); a1 += bf16hi(u0);
        b0 += bf16lo(u1); b1 += bf16hi(u1);
    }
    if (i < e) {
        unsigned u0 = h[(long)i * 64 + t];
        a0 += bf16lo(u0); a1 += bf16hi(u0);
    }
    a0 += b0; a1 += b1;
    float inv = (e > s) ? 1.0f / (float)(e - s) : 0.f;
    float2 o = { a0 * inv, a1 * inv };
    *(float2*)&hg[g * 128 + t * 2] = o;
}

// ---- mu/logvar heads + reparameterise ----
__global__ __launch_bounds__(64) void k_head(const float* __restrict__ hg,
        const float* __restrict__ Wmu, const float* __restrict__ bmu,
        const float* __restrict__ Wlv, const float* __restrict__ blv,
        const float* __restrict__ eps, float* __restrict__ mu_o, float* __restrict__ lv_o,
        float* __restrict__ z) {
    __shared__ float row[128];
    int g = blockIdx.x, t = threadIdx.x;
    row[t]      = hg[g * 128 + t];
    row[t + 64] = hg[g * 128 + t + 64];
    __syncthreads();
    float mu = bmu[t], lv = blv[t];
    for (int k = 0; k < 128; ++k) {
        float rv = row[k];
        mu += rv * Wmu[k * 64 + t];
        lv += rv * Wlv[k * 64 + t];
    }
    mu_o[g * 64 + t] = mu;
    lv_o[g * 64 + t] = lv;
    z[g * 64 + t] = mu + eps[g * 64 + t] * expf(0.5f * lv);
}

// ---- small MLP layer ----
__global__ __launch_bounds__(128) void k_mlp(const float* __restrict__ A, int K,
        const float* __restrict__ W, const float* __restrict__ b, float* __restrict__ out) {
    __shared__ float row[128];
    int m = blockIdx.x, t = threadIdx.x;
    if (t < K) row[t] = A[m * K + t];
    __syncthreads();
    float acc = b[t];
    for (int k = 0; k < K; ++k) acc += row[k] * W[k * 128 + t];
    out[m * 128 + t] = fmaxf(acc, 0.f);
}

// ---- probs = sigmoid(A @ D3 + d3); 8-row m-tiles ----
__global__ __launch_bounds__(256) void k_dec3(const float* __restrict__ A,
        const float* __restrict__ W, const float* __restrict__ b, float* __restrict__ out) {
    __shared__ float alds[8][128];
    int m0 = blockIdx.y * 8;
    for (int i = threadIdx.x; i < 8 * 128; i += 256)
        alds[i >> 7][i & 127] = A[(m0 + (i >> 7)) * 128 + (i & 127)];
    __syncthreads();
    if (threadIdx.x >= 254) return;
    int c = blockIdx.x * 1016 + threadIdx.x * 4;
    float4 bb = *(const float4*)&b[c];
    float4 acc[8];
    #pragma unroll
    for (int r = 0; r < 8; ++r) acc[r] = bb;
    for (int k = 0; k < 128; ++k) {
        float4 w = *(const float4*)&W[(long)k * OUTS + c];
        #pragma unroll
        for (int r = 0; r < 8; ++r) {
            float a = alds[r][k];
            acc[r].x += a * w.x; acc[r].y += a * w.y;
            acc[r].z += a * w.z; acc[r].w += a * w.w;
        }
    }
    #pragma unroll
    for (int r = 0; r < 8; ++r) {
        float4 o;
        o.x = 1.f / (1.f + expf(-acc[r].x));
        o.y = 1.f / (1.f + expf(-acc[r].y));
        o.z = 1.f / (1.f + expf(-acc[r].z));
        o.w = 1.f / (1.f + expf(-acc[r].w));
        *(float4*)&out[(long)(m0 + r) * OUTS + c] = o;
    }
}

// ---- build symmetric adjacency ----
__global__ __launch_bounds__(256) void k_adj(const float* __restrict__ probs, float* __restrict__ adj) {
    int t = blockIdx.x * 256 + threadIdx.x;
    int g = t >> 12;
    int rem = t & 4095;
    int r = rem >> 5;
    int c0 = (rem & 31) * 4;
    const float* pg = &probs[g * OUTS];
    float4 o;
    float* op = (float*)&o;
    #pragma unroll
    for (int j = 0; j < 4; ++j) {
        int c = c0 + j;
        if (c == r) { op[j] = 0.f; continue; }
        int a = c < r ? c : r;
        int b = c < r ? r : c;
        int k = a * (255 - a) / 2 + (b - a - 1);
        op[j] = pg[k];
    }
    *(float4*)&adj[(long)t * 4] = o;
}

extern "C" void kernel_launch(void* const* d_in, const int* in_sizes, int n_in,
                              void* d_out, int out_size, void* d_ws, size_t ws_size,
                              hipStream_t stream) {
    const float* x   = (const float*)d_in[0];
    const int*   ei  = (const int*)d_in[1];
    const int* batch = (const int*)d_in[2];
    const float* eps = (const float*)d_in[3];
    const float* W1  = (const float*)d_in[4];
    const float* b1  = (const float*)d_in[5];
    const float* W2  = (const float*)d_in[6];
    const float* b2  = (const float*)d_in[7];
    const float* Wmu = (const float*)d_in[8];
    const float* bmu = (const float*)d_in[9];
    const float* Wlv = (const float*)d_in[10];
    const float* blv = (const float*)d_in[11];
    const float* D1  = (const float*)d_in[12];
    const float* d1  = (const float*)d_in[13];
    const float* D2  = (const float*)d_in[14];
    const float* d2  = (const float*)d_in[15];
    const float* D3  = (const float*)d_in[16];
    const float* d3  = (const float*)d_in[17];

    const int* esrc = ei;
    const int* edst = ei + NE;

    float* out  = (float*)d_out;
    float* mu_o = out + 8388608;
    float* lv_o = mu_o + 32768;

    // --- CSR + small scratch in d_out (region fully overwritten by k_adj at the end) ---
    int*   colidx  = (int*)out;                 // 1,600,000
    int*   cnti    = colidx + 1600000;          // 100,000
    int*   rowptr  = cnti + 100000;             // 100,000
    int*   bsum    = rowptr + 100000;           // 128
    int*   boff    = bsum + 128;                // 128
    int*   seg_end = boff + 128;                // 512
    float* dinv    = (float*)(seg_end + 512);   // 100,000
    int*   bcur    = (int*)(dinv + 100000);     // 3,125
    int*   bbase   = bcur + NBUK;               // 3,125   (ends ~1.91M << 8.39M)

    // --- ws layout (float-unit offsets; ws_size >= 102.8MB proven round 1) ---
    float* ws = (float*)d_ws;
    unsigned* u1u = (unsigned*)ws;                         // 3.2M uints  [0 .. 3.2M)
    unsigned* s1u = u1u + 3200000;                         // 3.2M uints  [3.2M .. 6.4M)
    unsigned char* u2b = (unsigned char*)(ws + 6400000);   // 12.8M bytes [6.4M .. 9.6M)
    unsigned* s2u = (unsigned*)(ws + 9600000);             // 6.4M uints  [9.6M .. 16.0M)
    unsigned* h2b = (unsigned*)(ws + 16000000);            // 6.4M uints  [16.0M .. 22.4M)
    unsigned short* wt1 = (unsigned short*)(ws + 22400000);   // 8192 u16
    unsigned short* wt2 = wt1 + 8192;                         // 16384 u16
    int* tmp = (int*)(ws + 22420000);                      // 1.6M ints -> ends 24.02M floats
    // decoder scratch aliases u1/s1 (dead after gemm1)
    float* hg    = ws;
    float* zbuf  = hg + 65536;
    float* p1    = zbuf + 32768;
    float* p2    = p1 + 65536;
    float* probs = p2 + 65536;                             // 4.16M floats < 6.4M region

    // ---- CSR build ----
    hipMemsetAsync(cnti, 0, NN * sizeof(int), stream);
    hipMemsetAsync(bcur, 0, NBUK * sizeof(int), stream);
    k_deg<<<(NE + 255) / 256, 256, 0, stream>>>(edst, cnti);
    k_dinv<<<(NN + 255) / 256, 256, 0, stream>>>(cnti, dinv);
    k_scanA<<<98, 256, 0, stream>>>(cnti, rowptr, bsum);
    k_scanB<<<1, 128, 0, stream>>>(bsum, boff, 98);
    k_scanC<<<(NN + 255) / 256, 256, 0, stream>>>(rowptr, boff);
    k_bbase<<<(NBUK + 255) / 256, 256, 0, stream>>>(rowptr, bbase);
    k_bfill<<<(NE + 255) / 256, 256, 0, stream>>>(esrc, edst, bbase, bcur, tmp);
    k_csort<<<NBUK, 128, 0, stream>>>(bbase, rowptr, tmp, colidx);
    k_segend<<<(NN + 255) / 256, 256, 0, stream>>>(batch, seg_end);

    // ---- weights to bf16 (transposed) ----
    k_wt<64><<<32, 256, 0, stream>>>(W1, wt1);
    k_wt<128><<<64, 256, 0, stream>>>(W2, wt2);

    // ---- conv1 (gather in 64-ch x-space, then GEMM) ----
    k_scale_x<<<12500, 256, 0, stream>>>(x, dinv, u1u);
    k_gather1<<<12500, 256, 0, stream>>>(rowptr, cnti, colidx, u1u, dinv, s1u);
    k_gemm_mfma<64, 0><<<1563, 256, 0, stream>>>((const unsigned short*)s1u, wt1, dinv, b1, u2b);

    // ---- conv2 (gather fp8 128-ch, then GEMM) ----
    k_gather2<<<12500, 256, 0, stream>>>(rowptr, cnti, colidx, (const unsigned*)u2b, dinv, s2u);
    k_gemm_mfma<128, 1><<<1563, 256, 0, stream>>>((const unsigned short*)s2u, wt2, dinv, b2, h2b);

    // ---- pool + heads ----
    k_poolmean<<<NG, 64, 0, stream>>>(h2b, seg_end, hg);
    k_head<<<NG, 64, 0, stream>>>(hg, Wmu, bmu, Wlv, blv, eps, mu_o, lv_o, zbuf);

    // ---- decoder ----
    k_mlp<<<NG, 128, 0, stream>>>(zbuf, 64, D1, d1, p1);
    k_mlp<<<NG, 128, 0, stream>>>(p1, 128, D2, d2, p2);
    dim3 g3(8, 64);
    k_dec3<<<g3, 256, 0, stream>>>(p2, D3, d3, probs);
    k_adj<<<8192, 256, 0, stream>>>(probs, out);
}

// Round 6
// 394.976 us; speedup vs baseline: 1.9397x; 1.9397x over previous
//
#include <hip/hip_runtime.h>
#include <hip/hip_fp16.h>

#define NN 100000
#define NE 1600000
#define NG 512
#define OUTS 8128
#define NB2 196     // coarse buckets of 512 nodes (196*512 = 100352 >= NN)
#define CHUNK 8192
#define NPB 196     // ceil(NE/CHUNK)

typedef short bf16x8 __attribute__((ext_vector_type(8)));
typedef float f32x4 __attribute__((ext_vector_type(4)));

__device__ __forceinline__ unsigned pack_bf16x2(float a, float b) {
    unsigned ua = __float_as_uint(a);
    unsigned ub = __float_as_uint(b);
    ua = (ua + 0x7fffu + ((ua >> 16) & 1u)) >> 16;
    ub = (ub + 0x7fffu + ((ub >> 16) & 1u)) >> 16;
    return ua | (ub << 16);
}
__device__ __forceinline__ unsigned short f2bf(float f) {
    unsigned u = __float_as_uint(f);
    u = (u + 0x7fffu + ((u >> 16) & 1u)) >> 16;
    return (unsigned short)u;
}
__device__ __forceinline__ float bf16lo(unsigned u) { return __uint_as_float(u << 16); }
__device__ __forceinline__ float bf16hi(unsigned u) { return __uint_as_float(u & 0xffff0000u); }

// e4m3 encode for f >= 0 (relu'd): e4m3(v) == f16(v/256) with 10->3 mantissa round
__device__ __forceinline__ unsigned f2fp8(float f) {
    unsigned h = (unsigned)__half_as_ushort(__float2half(f * 0.00390625f));
    return (h + 0x3Fu + ((h >> 7) & 1u)) >> 7;
}
__device__ __forceinline__ float fp8tof(unsigned b) {
    unsigned short u = (unsigned short)(((b & 0x80u) << 8) | ((b & 0x7Fu) << 7));
    return __half2float(__ushort_as_half(u));
}

// ---- int degree ----
__global__ __launch_bounds__(256) void k_deg(const int* __restrict__ dst, int* __restrict__ cnt) {
    int e = blockIdx.x * 256 + threadIdx.x;
    if (e < NE) atomicAdd(&cnt[dst[e]], 1);
}

__global__ __launch_bounds__(256) void k_dinv(const int* __restrict__ cnt, float* __restrict__ dinv) {
    int i = blockIdx.x * 256 + threadIdx.x;
    if (i < NN) dinv[i] = rsqrtf((float)cnt[i] + 1.0f);
}

// ---- hierarchical exclusive scan ----
__global__ __launch_bounds__(256) void k_scanA(const int* __restrict__ cnt, int* __restrict__ pre,
                                               int* __restrict__ bsum) {
    __shared__ int lds[256];
    int base = blockIdx.x * 1024 + threadIdx.x * 4;
    int v0 = 0, v1 = 0, v2 = 0, v3 = 0;
    if (base + 3 < NN) {
        int4 c = *(const int4*)&cnt[base];
        v0 = c.x; v1 = c.y; v2 = c.z; v3 = c.w;
    } else {
        if (base + 0 < NN) v0 = cnt[base + 0];
        if (base + 1 < NN) v1 = cnt[base + 1];
        if (base + 2 < NN) v2 = cnt[base + 2];
    }
    int s = v0 + v1 + v2 + v3;
    lds[threadIdx.x] = s;
    __syncthreads();
    for (int off = 1; off < 256; off <<= 1) {
        int t = (threadIdx.x >= off) ? lds[threadIdx.x - off] : 0;
        __syncthreads();
        lds[threadIdx.x] += t;
        __syncthreads();
    }
    int excl = lds[threadIdx.x] - s;
    if (threadIdx.x == 255) bsum[blockIdx.x] = lds[255];
    if (base < NN) {
        int p0 = excl, p1 = p0 + v0, p2 = p1 + v1, p3 = p2 + v2;
        if (base + 3 < NN) { int4 o = {p0, p1, p2, p3}; *(int4*)&pre[base] = o; }
        else {
            pre[base] = p0;
            if (base + 1 < NN) pre[base + 1] = p1;
            if (base + 2 < NN) pre[base + 2] = p2;
        }
    }
}

__global__ void k_scanB(const int* __restrict__ bsum, int* __restrict__ boff, int nb) {
    __shared__ int lds[128];
    int v = (threadIdx.x < nb) ? bsum[threadIdx.x] : 0;
    lds[threadIdx.x] = v;
    __syncthreads();
    for (int off = 1; off < 128; off <<= 1) {
        int t = (threadIdx.x >= off) ? lds[threadIdx.x - off] : 0;
        __syncthreads();
        lds[threadIdx.x] += t;
        __syncthreads();
    }
    if (threadIdx.x < nb) boff[threadIdx.x] = lds[threadIdx.x] - v;
}

__global__ __launch_bounds__(256) void k_scanC(int* __restrict__ pre, const int* __restrict__ boff) {
    int i = blockIdx.x * 256 + threadIdx.x;
    if (i < NN) pre[i] += boff[i >> 10];
}

// ---- phase 1: per-block partition of an 8192-edge chunk into 196 coarse buckets ----
// writes grouped edges into the block's PRIVATE tmp region (no global atomics)
__global__ __launch_bounds__(256) void k_part(const int* __restrict__ src, const int* __restrict__ dst,
        int* __restrict__ tmp, int* __restrict__ scanhist) {
    __shared__ int hist[NB2], cur[NB2], scan[256];
    int p = blockIdx.x, t = threadIdx.x;
    int e0 = p * CHUNK;
    int e1 = min(e0 + CHUNK, NE);
    for (int i = t; i < NB2; i += 256) hist[i] = 0;
    __syncthreads();
    for (int e = e0 + t; e < e1; e += 256)
        atomicAdd(&hist[dst[e] >> 9], 1);
    __syncthreads();
    int h = (t < NB2) ? hist[t] : 0;
    scan[t] = h;
    __syncthreads();
    for (int off = 1; off < 256; off <<= 1) {
        int v = (t >= off) ? scan[t - off] : 0;
        __syncthreads();
        scan[t] += v;
        __syncthreads();
    }
    if (t < NB2) {
        int excl = scan[t] - h;
        cur[t] = excl;
        scanhist[p * (NB2 + 1) + t] = excl;
    }
    if (t == 0) scanhist[p * (NB2 + 1) + NB2] = e1 - e0;
    __syncthreads();
    for (int e = e0 + t; e < e1; e += 256) {
        int d = dst[e];
        int b = d >> 9;
        int r = atomicAdd(&cur[b], 1);          // LDS atomic only
        tmp[e0 + r] = (src[e] << 9) | (d & 511);
    }
}

// ---- phase 2: per-bucket counting sort into colidx (LDS cursors, contiguous region) ----
__global__ __launch_bounds__(256) void k_fill2(const int* __restrict__ rowptr,
        const int* __restrict__ scanhist, const int* __restrict__ tmp, int* __restrict__ colidx) {
    __shared__ int rb[512], lc[512];
    int b = blockIdx.x;
    int n0 = b << 9;
    for (int i = threadIdx.x; i < 512; i += 256) {
        int node = n0 + i;
        rb[i] = (node < NN) ? rowptr[node] : 0;
        lc[i] = 0;
    }
    __syncthreads();
    int w = threadIdx.x >> 6, lane = threadIdx.x & 63;
    for (int p = w; p < NPB; p += 4) {
        int s0 = scanhist[p * (NB2 + 1) + b];
        int s1 = scanhist[p * (NB2 + 1) + b + 1];
        int base = p * CHUNK;
        for (int i = s0 + lane; i < s1; i += 64) {
            int v = tmp[base + i];
            int dl = v & 511;
            int pos = atomicAdd(&lc[dl], 1);    // LDS atomic only
            colidx[rb[dl] + pos] = v >> 9;
        }
    }
}

// ---- segment ends from sorted batch ----
__global__ __launch_bounds__(256) void k_segend(const int* __restrict__ batch, int* __restrict__ seg_end) {
    int i = blockIdx.x * 256 + threadIdx.x;
    if (i >= NN) return;
    int b = batch[i];
    int bn = (i == NN - 1) ? NG : batch[i + 1];
    for (int g = b; g < bn; ++g) seg_end[g] = i + 1;
    if (i == 0) {
        for (int g = 0; g < b; ++g) seg_end[g] = 0;
    }
}

// ---- W[K][128] fp32 -> WT[128][K] bf16 ----
template<int K>
__global__ __launch_bounds__(256) void k_wt(const float* __restrict__ W, unsigned short* __restrict__ wt) {
    int e = blockIdx.x * 256 + threadIdx.x;
    int n = e / K, k = e - n * K;
    wt[e] = f2bf(W[k * 128 + n]);
}

// ---- u1 = bf16(x * dinv[row]), 64ch ----
__global__ __launch_bounds__(256) void k_scale_x(const float* __restrict__ x,
        const float* __restrict__ dinv, unsigned* __restrict__ u1) {
    int i = blockIdx.x * 256 + threadIdx.x;   // < NN*32
    int row = i >> 5, c = i & 31;
    float2 v = *(const float2*)&x[(long)row * 64 + c * 2];
    float d = dinv[row];
    u1[i] = pack_bf16x2(v.x * d, v.y * d);
}

// ---- gather1: s1 = bf16(dinv_n * (u1[n] + sum u1[src])), 64ch; 32 lanes/node ----
__global__ __launch_bounds__(256) void k_gather1(const int* __restrict__ rowptr,
        const int* __restrict__ cnti, const int* __restrict__ colidx,
        const unsigned* __restrict__ u, const float* __restrict__ dinv,
        unsigned* __restrict__ s1) {
    int node = blockIdx.x * 8 + (threadIdx.x >> 5);
    int lane = threadIdx.x & 31;
    unsigned uu = u[node * 32 + lane];
    float a0 = bf16lo(uu), a1 = bf16hi(uu);
    float b0 = 0.f, b1 = 0.f;
    int n = cnti[node];
    const int* ci = colidx + rowptr[node];
    int j = 0;
    for (; j + 2 <= n; j += 2) {
        unsigned u0 = u[ci[j] * 32 + lane];
        unsigned u1v = u[ci[j + 1] * 32 + lane];
        a0 += bf16lo(u0); a1 += bf16hi(u0);
        b0 += bf16lo(u1v); b1 += bf16hi(u1v);
    }
    if (j < n) {
        unsigned u0 = u[ci[j] * 32 + lane];
        a0 += bf16lo(u0); a1 += bf16hi(u0);
    }
    a0 += b0; a1 += b1;
    float d = dinv[node];
    s1[node * 32 + lane] = pack_bf16x2(a0 * d, a1 * d);
}

// ---- gather2: s2 = bf16(16*dinv_n * (q[n] + sum q[src])), q fp8, 128ch ----
__global__ __launch_bounds__(256) void k_gather2(const int* __restrict__ rowptr,
        const int* __restrict__ cnti, const int* __restrict__ colidx,
        const unsigned* __restrict__ u, const float* __restrict__ dinv,
        unsigned* __restrict__ s2) {
    int node = blockIdx.x * 8 + (threadIdx.x >> 5);
    int lane = threadIdx.x & 31;
    unsigned uu = u[node * 32 + lane];
    float a0 = fp8tof(uu & 255), a1 = fp8tof((uu >> 8) & 255);
    float a2 = fp8tof((uu >> 16) & 255), a3 = fp8tof(uu >> 24);
    float b0 = 0.f, b1 = 0.f, b2 = 0.f, b3 = 0.f;
    int n = cnti[node];
    const int* ci = colidx + rowptr[node];
    int j = 0;
    for (; j + 2 <= n; j += 2) {
        unsigned v0 = u[ci[j] * 32 + lane];
        unsigned v1 = u[ci[j + 1] * 32 + lane];
        a0 += fp8tof(v0 & 255); a1 += fp8tof((v0 >> 8) & 255);
        a2 += fp8tof((v0 >> 16) & 255); a3 += fp8tof(v0 >> 24);
        b0 += fp8tof(v1 & 255); b1 += fp8tof((v1 >> 8) & 255);
        b2 += fp8tof((v1 >> 16) & 255); b3 += fp8tof(v1 >> 24);
    }
    if (j < n) {
        unsigned v0 = u[ci[j] * 32 + lane];
        a0 += fp8tof(v0 & 255); a1 += fp8tof((v0 >> 8) & 255);
        a2 += fp8tof((v0 >> 16) & 255); a3 += fp8tof(v0 >> 24);
    }
    a0 += b0; a1 += b1; a2 += b2; a3 += b3;
    float d = dinv[node] * 16.0f;
    uint2 o;
    o.x = pack_bf16x2(a0 * d, a1 * d);
    o.y = pack_bf16x2(a2 * d, a3 * d);
    *(uint2*)&s2[node * 64 + lane * 2] = o;
}

// ---- MFMA GEMM: h = relu(A@W + bias); EPI 0: out fp8(16*dinv*h); EPI 1: out bf16 ----
template<int K, int EPI>
__global__ __launch_bounds__(256) void k_gemm_mfma(const unsigned short* __restrict__ Ab,
        const unsigned short* __restrict__ wt, const float* __restrict__ dinv,
        const float* __restrict__ bias, void* __restrict__ outp) {
    constexpr int KS = K / 32;
    constexpr int SLOTS = K / 8;
    __shared__ __align__(16) unsigned short wlds[128 * K];
    char* lb = (char*)wlds;
    for (int c = threadIdx.x; c < 128 * SLOTS; c += 256) {
        int n = c / SLOTS, s = c - n * SLOTS;
        *(uint4*)(lb + n * (2 * K) + ((s ^ (n & 7)) << 4)) = *(const uint4*)(wt + c * 8);
    }
    __syncthreads();
    int lane = threadIdx.x & 63;
    int w = threadIdx.x >> 6;
    int r0 = blockIdx.x * 64 + w * 16;
    int arow = r0 + (lane & 15);
    if (arow >= NN) arow = NN - 1;
    bf16x8 af[KS];
    #pragma unroll
    for (int ks = 0; ks < KS; ++ks)
        af[ks] = *(const bf16x8*)&Ab[(long)arow * K + ks * 32 + (lane >> 4) * 8];
    f32x4 acc[8];
    #pragma unroll
    for (int t = 0; t < 8; ++t) acc[t] = (f32x4){0.f, 0.f, 0.f, 0.f};
    #pragma unroll
    for (int ks = 0; ks < KS; ++ks) {
        #pragma unroll
        for (int t = 0; t < 8; ++t) {
            int n = t * 16 + (lane & 15);
            int slot = ks * 4 + (lane >> 4);
            bf16x8 bf = *(const bf16x8*)(lb + n * (2 * K) + ((slot ^ (n & 7)) << 4));
            acc[t] = __builtin_amdgcn_mfma_f32_16x16x32_bf16(af[ks], bf, acc[t], 0, 0, 0);
        }
    }
    float bv[8];
    #pragma unroll
    for (int t = 0; t < 8; ++t) bv[t] = bias[t * 16 + (lane & 15)];
    #pragma unroll
    for (int r = 0; r < 4; ++r) {
        long row = r0 + (lane >> 4) * 4 + r;
        if (row >= NN) continue;
        float d = dinv[row];
        #pragma unroll
        for (int t = 0; t < 8; ++t) {
            float val = fmaxf(acc[t][r] + bv[t], 0.f);
            int col = t * 16 + (lane & 15);
            if (EPI == 0)
                ((unsigned char*)outp)[row * 128 + col] = (unsigned char)f2fp8(val * (16.0f * d));
            else
                ((unsigned short*)outp)[row * 128 + col] = f2bf(val);
        }
    }
}

// ---- segmented mean pool over bf16 h2: 4 waves per graph ----
__global__ __launch_bounds__(256) void k_poolmean(const unsigned* __restrict__ h,
        const int* __restrict__ seg_end, float* __restrict__ hg) {
    __shared__ float part[3][128];
    int g = blockIdx.x;
    int w = threadIdx.x >> 6, t = threadIdx.x & 63;
    int s = (g == 0) ? 0 : seg_end[g - 1];
    int e = seg_end[g];
    float a0 = 0.f, a1 = 0.f;
    for (int i = s + w; i < e; i += 4) {
        unsigned u = h[(long)i * 64 + t];
        a0 += bf16lo(u); a1 += bf16hi(u);
    }
    if (w) { part[w - 1][t * 2] = a0; part[w - 1][t * 2 + 1] = a1; }
    __syncthreads();
    if (w == 0) {
        a0 += part[0][t * 2] + part[1][t * 2] + part[2][t * 2];
        a1 += part[0][t * 2 + 1] + part[1][t * 2 + 1] + part[2][t * 2 + 1];
        float inv = (e > s) ? 1.0f / (float)(e - s) : 0.f;
        float2 o = { a0 * inv, a1 * inv };
        *(float2*)&hg[g * 128 + t * 2] = o;
    }
}

// ---- mu/logvar heads + reparameterise ----
__global__ __launch_bounds__(64) void k_head(const float* __restrict__ hg,
        const float* __restrict__ Wmu, const float* __restrict__ bmu,
        const float* __restrict__ Wlv, const float* __restrict__ blv,
        const float* __restrict__ eps, float* __restrict__ mu_o, float* __restrict__ lv_o,
        float* __restrict__ z) {
    __shared__ float row[128];
    int g = blockIdx.x, t = threadIdx.x;
    row[t]      = hg[g * 128 + t];
    row[t + 64] = hg[g * 128 + t + 64];
    __syncthreads();
    float mu = bmu[t], lv = blv[t];
    for (int k = 0; k < 128; ++k) {
        float rv = row[k];
        mu += rv * Wmu[k * 64 + t];
        lv += rv * Wlv[k * 64 + t];
    }
    mu_o[g * 64 + t] = mu;
    lv_o[g * 64 + t] = lv;
    z[g * 64 + t] = mu + eps[g * 64 + t] * expf(0.5f * lv);
}

// ---- small MLP layer ----
__global__ __launch_bounds__(128) void k_mlp(const float* __restrict__ A, int K,
        const float* __restrict__ W, const float* __restrict__ b, float* __restrict__ out) {
    __shared__ float row[128];
    int m = blockIdx.x, t = threadIdx.x;
    if (t < K) row[t] = A[m * K + t];
    __syncthreads();
    float acc = b[t];
    for (int k = 0; k < K; ++k) acc += row[k] * W[k * 128 + t];
    out[m * 128 + t] = fmaxf(acc, 0.f);
}

// ---- probs = sigmoid(A @ D3 + d3); 16-row m-tiles ----
__global__ __launch_bounds__(256) void k_dec3(const float* __restrict__ A,
        const float* __restrict__ W, const float* __restrict__ b, float* __restrict__ out) {
    __shared__ float alds[16][128];
    int m0 = blockIdx.y * 16;
    for (int i = threadIdx.x; i < 16 * 128; i += 256)
        alds[i >> 7][i & 127] = A[(m0 + (i >> 7)) * 128 + (i & 127)];
    __syncthreads();
    if (threadIdx.x >= 254) return;
    int c = blockIdx.x * 1016 + threadIdx.x * 4;
    float4 bb = *(const float4*)&b[c];
    float4 acc[16];
    #pragma unroll
    for (int r = 0; r < 16; ++r) acc[r] = bb;
    for (int k = 0; k < 128; ++k) {
        float4 w = *(const float4*)&W[(long)k * OUTS + c];
        #pragma unroll
        for (int r = 0; r < 16; ++r) {
            float a = alds[r][k];
            acc[r].x += a * w.x; acc[r].y += a * w.y;
            acc[r].z += a * w.z; acc[r].w += a * w.w;
        }
    }
    #pragma unroll
    for (int r = 0; r < 16; ++r) {
        float4 o;
        o.x = 1.f / (1.f + expf(-acc[r].x));
        o.y = 1.f / (1.f + expf(-acc[r].y));
        o.z = 1.f / (1.f + expf(-acc[r].z));
        o.w = 1.f / (1.f + expf(-acc[r].w));
        *(float4*)&out[(long)(m0 + r) * OUTS + c] = o;
    }
}

// ---- build symmetric adjacency ----
__global__ __launch_bounds__(256) void k_adj(const float* __restrict__ probs, float* __restrict__ adj) {
    int t = blockIdx.x * 256 + threadIdx.x;
    int g = t >> 12;
    int rem = t & 4095;
    int r = rem >> 5;
    int c0 = (rem & 31) * 4;
    const float* pg = &probs[g * OUTS];
    float4 o;
    float* op = (float*)&o;
    #pragma unroll
    for (int j = 0; j < 4; ++j) {
        int c = c0 + j;
        if (c == r) { op[j] = 0.f; continue; }
        int a = c < r ? c : r;
        int b = c < r ? r : c;
        int k = a * (255 - a) / 2 + (b - a - 1);
        op[j] = pg[k];
    }
    *(float4*)&adj[(long)t * 4] = o;
}

extern "C" void kernel_launch(void* const* d_in, const int* in_sizes, int n_in,
                              void* d_out, int out_size, void* d_ws, size_t ws_size,
                              hipStream_t stream) {
    const float* x   = (const float*)d_in[0];
    const int*   ei  = (const int*)d_in[1];
    const int* batch = (const int*)d_in[2];
    const float* eps = (const float*)d_in[3];
    const float* W1  = (const float*)d_in[4];
    const float* b1  = (const float*)d_in[5];
    const float* W2  = (const float*)d_in[6];
    const float* b2  = (const float*)d_in[7];
    const float* Wmu = (const float*)d_in[8];
    const float* bmu = (const float*)d_in[9];
    const float* Wlv = (const float*)d_in[10];
    const float* blv = (const float*)d_in[11];
    const float* D1  = (const float*)d_in[12];
    const float* d1  = (const float*)d_in[13];
    const float* D2  = (const float*)d_in[14];
    const float* d2  = (const float*)d_in[15];
    const float* D3  = (const float*)d_in[16];
    const float* d3  = (const float*)d_in[17];

    const int* esrc = ei;
    const int* edst = ei + NE;

    float* out  = (float*)d_out;
    float* mu_o = out + 8388608;
    float* lv_o = mu_o + 32768;

    // --- CSR + small scratch in d_out (region fully overwritten by k_adj at the end) ---
    int*   colidx  = (int*)out;                 // 1,600,000
    int*   cnti    = colidx + 1600000;          // 100,000
    int*   rowptr  = cnti + 100000;             // 100,000
    int*   bsum    = rowptr + 100000;           // 128
    int*   boff    = bsum + 128;                // 128
    int*   seg_end = boff + 128;                // 512
    float* dinv    = (float*)(seg_end + 512);   // 100,000
    int*   scanhist = (int*)(dinv + 100000);    // 196*197 = 38,612 (ends ~1.94M << 8.39M)

    // --- ws layout (float-unit offsets) ---
    float* ws = (float*)d_ws;
    unsigned* u1u = (unsigned*)ws;                         // 3.2M uints
    unsigned* s1u = u1u + 3200000;                         // 3.2M uints
    unsigned char* u2b = (unsigned char*)(ws + 6400000);   // 12.8M bytes
    unsigned* s2u = (unsigned*)(ws + 9600000);             // 6.4M uints
    unsigned* h2b = (unsigned*)(ws + 16000000);            // 6.4M uints
    unsigned short* wt1 = (unsigned short*)(ws + 22400000);   // 8192 u16
    unsigned short* wt2 = wt1 + 8192;                         // 16384 u16
    int* tmp = (int*)(ws + 22420000);                      // 1.6M+ ints
    // decoder scratch aliases u1/s1 (dead after gemm1)
    float* hg    = ws;
    float* zbuf  = hg + 65536;
    float* p1    = zbuf + 32768;
    float* p2    = p1 + 65536;
    float* probs = p2 + 65536;

    // ---- CSR build (two-phase partition, LDS atomics only) ----
    hipMemsetAsync(cnti, 0, NN * sizeof(int), stream);
    k_deg<<<(NE + 255) / 256, 256, 0, stream>>>(edst, cnti);
    k_dinv<<<(NN + 255) / 256, 256, 0, stream>>>(cnti, dinv);
    k_scanA<<<98, 256, 0, stream>>>(cnti, rowptr, bsum);
    k_scanB<<<1, 128, 0, stream>>>(bsum, boff, 98);
    k_scanC<<<(NN + 255) / 256, 256, 0, stream>>>(rowptr, boff);
    k_part<<<NPB, 256, 0, stream>>>(esrc, edst, tmp, scanhist);
    k_fill2<<<NB2, 256, 0, stream>>>(rowptr, scanhist, tmp, colidx);
    k_segend<<<(NN + 255) / 256, 256, 0, stream>>>(batch, seg_end);

    // ---- weights to bf16 (transposed) ----
    k_wt<64><<<32, 256, 0, stream>>>(W1, wt1);
    k_wt<128><<<64, 256, 0, stream>>>(W2, wt2);

    // ---- conv1 (gather in 64-ch x-space, then GEMM) ----
    k_scale_x<<<12500, 256, 0, stream>>>(x, dinv, u1u);
    k_gather1<<<12500, 256, 0, stream>>>(rowptr, cnti, colidx, u1u, dinv, s1u);
    k_gemm_mfma<64, 0><<<1563, 256, 0, stream>>>((const unsigned short*)s1u, wt1, dinv, b1, u2b);

    // ---- conv2 (gather fp8 128-ch, then GEMM) ----
    k_gather2<<<12500, 256, 0, stream>>>(rowptr, cnti, colidx, (const unsigned*)u2b, dinv, s2u);
    k_gemm_mfma<128, 1><<<1563, 256, 0, stream>>>((const unsigned short*)s2u, wt2, dinv, b2, h2b);

    // ---- pool + heads ----
    k_poolmean<<<NG, 256, 0, stream>>>(h2b, seg_end, hg);
    k_head<<<NG, 64, 0, stream>>>(hg, Wmu, bmu, Wlv, blv, eps, mu_o, lv_o, zbuf);

    // ---- decoder ----
    k_mlp<<<NG, 128, 0, stream>>>(zbuf, 64, D1, d1, p1);
    k_mlp<<<NG, 128, 0, stream>>>(p1, 128, D2, d2, p2);
    dim3 g3(8, 32);
    k_dec3<<<g3, 256, 0, stream>>>(p2, D3, d3, probs);
    k_adj<<<8192, 256, 0, stream>>>(probs, out);
}

// Round 8
// 330.539 us; speedup vs baseline: 2.3178x; 1.1949x over previous
//
#include <hip/hip_runtime.h>
#include <hip/hip_fp16.h>

#define NN 100000
#define NE 1600000
#define NG 512
#define OUTS 8128
#define NB2 196     // coarse buckets of 512 nodes (196*512 = 100352 >= NN)
#define CHUNK 8192
#define NPB 196     // ceil(NE/CHUNK)

typedef short bf16x8 __attribute__((ext_vector_type(8)));
typedef _Float16 f16x8 __attribute__((ext_vector_type(8)));
typedef _Float16 f16x2 __attribute__((ext_vector_type(2)));
typedef float f32x4 __attribute__((ext_vector_type(4)));

__device__ __forceinline__ unsigned pack_bf16x2(float a, float b) {
    unsigned ua = __float_as_uint(a);
    unsigned ub = __float_as_uint(b);
    ua = (ua + 0x7fffu + ((ua >> 16) & 1u)) >> 16;
    ub = (ub + 0x7fffu + ((ub >> 16) & 1u)) >> 16;
    return ua | (ub << 16);
}
__device__ __forceinline__ unsigned short f2bf(float f) {
    unsigned u = __float_as_uint(f);
    u = (u + 0x7fffu + ((u >> 16) & 1u)) >> 16;
    return (unsigned short)u;
}
// f32 pair -> packed f16x2 (RTZ), as raw uint
__device__ __forceinline__ unsigned cvt_pkrtz_u(float a, float b) {
    auto h = __builtin_amdgcn_cvt_pkrtz(a, b);
    union { decltype(h) h2; unsigned u; } c; c.h2 = h; return c.u;
}
__device__ __forceinline__ f16x2 u2h(unsigned u) { union { unsigned u; f16x2 h; } c; c.u = u; return c.h; }
__device__ __forceinline__ unsigned h2u(f16x2 h) { union { f16x2 h; unsigned u; } c; c.h = h; return c.u; }

// e4m3 encode for f >= 0 (relu'd): e4m3(v) == f16(v/256) with 10->3 mantissa round
__device__ __forceinline__ unsigned f2fp8(float f) {
    unsigned h = (unsigned)__half_as_ushort(__float2half(f * 0.00390625f));
    return (h + 0x3Fu + ((h >> 7) & 1u)) >> 7;
}

// ---- phase 1: per-block partition of an 8192-edge chunk into 196 coarse buckets ----
__global__ __launch_bounds__(256) void k_part(const int* __restrict__ src, const int* __restrict__ dst,
        int* __restrict__ tmp, int* __restrict__ scanhist) {
    __shared__ int hist[NB2], cur[NB2], scan[256];
    int p = blockIdx.x, t = threadIdx.x;
    int e0 = p * CHUNK;
    int e1 = min(e0 + CHUNK, NE);
    for (int i = t; i < NB2; i += 256) hist[i] = 0;
    __syncthreads();
    for (int e = e0 + t; e < e1; e += 256)
        atomicAdd(&hist[dst[e] >> 9], 1);
    __syncthreads();
    int h = (t < NB2) ? hist[t] : 0;
    scan[t] = h;
    __syncthreads();
    for (int off = 1; off < 256; off <<= 1) {
        int v = (t >= off) ? scan[t - off] : 0;
        __syncthreads();
        scan[t] += v;
        __syncthreads();
    }
    if (t < NB2) {
        int excl = scan[t] - h;
        cur[t] = excl;
        scanhist[p * (NB2 + 1) + t] = excl;
    }
    if (t == 0) scanhist[p * (NB2 + 1) + NB2] = e1 - e0;
    __syncthreads();
    for (int e = e0 + t; e < e1; e += 256) {
        int d = dst[e];
        int b = d >> 9;
        int r = atomicAdd(&cur[b], 1);          // LDS atomic only
        tmp[e0 + r] = (src[e] << 9) | (d & 511);
    }
}

// ---- bucket totals + exclusive scan -> bucketbase (1 block) ----
__global__ __launch_bounds__(256) void k_btot(const int* __restrict__ scanhist, int* __restrict__ bucketbase) {
    __shared__ int sc[256];
    int b = threadIdx.x;
    int tot = 0;
    if (b < NB2) {
        for (int p = 0; p < NPB; ++p)
            tot += scanhist[p * (NB2 + 1) + b + 1] - scanhist[p * (NB2 + 1) + b];
    }
    sc[b] = tot;
    __syncthreads();
    for (int off = 1; off < 256; off <<= 1) {
        int v = (b >= off) ? sc[b - off] : 0;
        __syncthreads();
        sc[b] += v;
        __syncthreads();
    }
    if (b < NB2) bucketbase[b] = sc[b] - tot;
}

// ---- phase 2: per-bucket count + scan + place; emits cnti/rowptr/dinv/colidx ----
__global__ __launch_bounds__(256) void k_fill2(const int* __restrict__ bucketbase,
        const int* __restrict__ scanhist, const int* __restrict__ tmp,
        int* __restrict__ colidx, int* __restrict__ cnti, int* __restrict__ rowptr,
        float* __restrict__ dinv) {
    __shared__ int lc[512], rb[512], sc[256];
    int b = blockIdx.x, t = threadIdx.x;
    int n0 = b << 9;
    lc[t] = 0; lc[t + 256] = 0;
    __syncthreads();
    int w = t >> 6, lane = t & 63;
    // count phase
    for (int p = w; p < NPB; p += 4) {
        int s0 = scanhist[p * (NB2 + 1) + b];
        int s1 = scanhist[p * (NB2 + 1) + b + 1];
        int base = p * CHUNK;
        for (int i = s0 + lane; i < s1; i += 64)
            atomicAdd(&lc[tmp[base + i] & 511], 1);
    }
    __syncthreads();
    // scan 512 via 256 pair-partials
    int v0 = lc[2 * t], v1 = lc[2 * t + 1];
    int s = v0 + v1;
    sc[t] = s;
    __syncthreads();
    for (int off = 1; off < 256; off <<= 1) {
        int v = (t >= off) ? sc[t - off] : 0;
        __syncthreads();
        sc[t] += v;
        __syncthreads();
    }
    int excl = sc[t] - s;
    int base0 = bucketbase[b];
    rb[2 * t] = base0 + excl;
    rb[2 * t + 1] = base0 + excl + v0;
    int node0 = n0 + 2 * t;
    if (node0 < NN) {
        cnti[node0] = v0;
        rowptr[node0] = base0 + excl;
        dinv[node0] = rsqrtf((float)v0 + 1.0f);
    }
    if (node0 + 1 < NN) {
        cnti[node0 + 1] = v1;
        rowptr[node0 + 1] = base0 + excl + v0;
        dinv[node0 + 1] = rsqrtf((float)v1 + 1.0f);
    }
    lc[2 * t] = 0; lc[2 * t + 1] = 0;
    __syncthreads();
    // place phase
    for (int p = w; p < NPB; p += 4) {
        int s0 = scanhist[p * (NB2 + 1) + b];
        int s1 = scanhist[p * (NB2 + 1) + b + 1];
        int base = p * CHUNK;
        for (int i = s0 + lane; i < s1; i += 64) {
            int v = tmp[base + i];
            int dl = v & 511;
            int pos = atomicAdd(&lc[dl], 1);    // LDS atomic only
            colidx[rb[dl] + pos] = v >> 9;
        }
    }
}

// ---- segment ends from sorted batch ----
__global__ __launch_bounds__(256) void k_segend(const int* __restrict__ batch, int* __restrict__ seg_end) {
    int i = blockIdx.x * 256 + threadIdx.x;
    if (i >= NN) return;
    int b = batch[i];
    int bn = (i == NN - 1) ? NG : batch[i + 1];
    for (int g = b; g < bn; ++g) seg_end[g] = i + 1;
    if (i == 0) {
        for (int g = 0; g < b; ++g) seg_end[g] = 0;
    }
}

// ---- W[K][128] fp32 -> WT[128][K]; F16=1 -> f16 bits, else bf16 ----
template<int K, int F16>
__global__ __launch_bounds__(256) void k_wt(const float* __restrict__ W, unsigned short* __restrict__ wt) {
    int e = blockIdx.x * 256 + threadIdx.x;
    int n = e / K, k = e - n * K;
    float v = W[k * 128 + n];
    wt[e] = F16 ? (unsigned short)__half_as_ushort(__float2half(v)) : f2bf(v);
}

// ---- u1 = f16(x * dinv[row]), 64ch ----
__global__ __launch_bounds__(256) void k_scale_x(const float* __restrict__ x,
        const float* __restrict__ dinv, unsigned* __restrict__ u1) {
    int i = blockIdx.x * 256 + threadIdx.x;   // < NN*32
    int row = i >> 5, c = i & 31;
    float2 v = *(const float2*)&x[(long)row * 64 + c * 2];
    float d = dinv[row];
    u1[i] = cvt_pkrtz_u(v.x * d, v.y * d);
}

// ---- gather1: s1 = f16(dinv_n * (u1[n] + sum u1[src])), 64ch f16, v_pk_add_f16 ----
__global__ __launch_bounds__(256) void k_gather1(const int* __restrict__ rowptr,
        const int* __restrict__ cnti, const int* __restrict__ colidx,
        const unsigned* __restrict__ u, const float* __restrict__ dinv,
        unsigned* __restrict__ s1) {
    int node = blockIdx.x * 8 + (threadIdx.x >> 5);
    int lane = threadIdx.x & 31;
    const f16x2* uf = (const f16x2*)u;
    f16x2 acc = uf[node * 32 + lane];
    f16x2 acc2 = {(_Float16)0.f, (_Float16)0.f};
    int n = cnti[node];
    const int* ci = colidx + rowptr[node];
    int j = 0;
    for (; j + 2 <= n; j += 2) {
        f16x2 a = uf[ci[j] * 32 + lane];
        f16x2 b = uf[ci[j + 1] * 32 + lane];
        acc += a;
        acc2 += b;
    }
    if (j < n) acc += uf[ci[j] * 32 + lane];
    acc += acc2;
    float d = dinv[node];
    s1[node * 32 + lane] = cvt_pkrtz_u((float)acc[0] * d, (float)acc[1] * d);
}

// ---- gather2: s2 = bf16(16*dinv_n * sum fp8rows), packed decode (sign-free), pk_add_f16 ----
__global__ __launch_bounds__(256) void k_gather2(const int* __restrict__ rowptr,
        const int* __restrict__ cnti, const int* __restrict__ colidx,
        const unsigned* __restrict__ u, const float* __restrict__ dinv,
        unsigned* __restrict__ s2) {
    int node = blockIdx.x * 8 + (threadIdx.x >> 5);
    int lane = threadIdx.x & 31;
    unsigned uu = u[node * 32 + lane];
    f16x2 acc0 = u2h((uu & 0x007f007fu) << 7);   // ch0, ch2
    f16x2 acc1 = u2h((uu & 0x7f007f00u) >> 1);   // ch1, ch3
    f16x2 bcc0 = {(_Float16)0.f, (_Float16)0.f};
    f16x2 bcc1 = {(_Float16)0.f, (_Float16)0.f};
    int n = cnti[node];
    const int* ci = colidx + rowptr[node];
    int j = 0;
    for (; j + 2 <= n; j += 2) {
        unsigned w0 = u[ci[j] * 32 + lane];
        unsigned w1 = u[ci[j + 1] * 32 + lane];
        acc0 += u2h((w0 & 0x007f007fu) << 7);
        acc1 += u2h((w0 & 0x7f007f00u) >> 1);
        bcc0 += u2h((w1 & 0x007f007fu) << 7);
        bcc1 += u2h((w1 & 0x7f007f00u) >> 1);
    }
    if (j < n) {
        unsigned w0 = u[ci[j] * 32 + lane];
        acc0 += u2h((w0 & 0x007f007fu) << 7);
        acc1 += u2h((w0 & 0x7f007f00u) >> 1);
    }
    acc0 += bcc0;
    acc1 += bcc1;
    float d = dinv[node] * 16.0f;   // *256 (decode) / 16 (encode scale)
    float a0 = (float)acc0[0], a2 = (float)acc0[1];
    float a1 = (float)acc1[0], a3 = (float)acc1[1];
    uint2 o;
    o.x = pack_bf16x2(a0 * d, a1 * d);
    o.y = pack_bf16x2(a2 * d, a3 * d);
    *(uint2*)&s2[node * 64 + lane * 2] = o;
}

// ---- MFMA GEMM: h = relu(A@W + bias); AF16: f16 inputs; EPI 0: out fp8(16*dinv*h); 1: bf16 ----
template<int K, int EPI, int AF16>
__global__ __launch_bounds__(256) void k_gemm_mfma(const unsigned short* __restrict__ Ab,
        const unsigned short* __restrict__ wt, const float* __restrict__ dinv,
        const float* __restrict__ bias, void* __restrict__ outp) {
    constexpr int KS = K / 32;
    constexpr int SLOTS = K / 8;
    __shared__ __align__(16) unsigned short wlds[128 * K];
    char* lb = (char*)wlds;
    for (int c = threadIdx.x; c < 128 * SLOTS; c += 256) {
        int n = c / SLOTS, s = c - n * SLOTS;
        *(uint4*)(lb + n * (2 * K) + ((s ^ (n & 7)) << 4)) = *(const uint4*)(wt + c * 8);
    }
    __syncthreads();
    int lane = threadIdx.x & 63;
    int w = threadIdx.x >> 6;
    int r0 = blockIdx.x * 64 + w * 16;
    int arow = r0 + (lane & 15);
    if (arow >= NN) arow = NN - 1;
    bf16x8 af[KS];
    #pragma unroll
    for (int ks = 0; ks < KS; ++ks)
        af[ks] = *(const bf16x8*)&Ab[(long)arow * K + ks * 32 + (lane >> 4) * 8];
    f32x4 acc[8];
    #pragma unroll
    for (int t = 0; t < 8; ++t) acc[t] = (f32x4){0.f, 0.f, 0.f, 0.f};
    #pragma unroll
    for (int ks = 0; ks < KS; ++ks) {
        #pragma unroll
        for (int t = 0; t < 8; ++t) {
            int n = t * 16 + (lane & 15);
            int slot = ks * 4 + (lane >> 4);
            bf16x8 braw = *(const bf16x8*)(lb + n * (2 * K) + ((slot ^ (n & 7)) << 4));
            if constexpr (AF16) {
                union { bf16x8 r; f16x8 h; } ca, cb;
                ca.r = af[ks]; cb.r = braw;
                acc[t] = __builtin_amdgcn_mfma_f32_16x16x32_f16(ca.h, cb.h, acc[t], 0, 0, 0);
            } else {
                acc[t] = __builtin_amdgcn_mfma_f32_16x16x32_bf16(af[ks], braw, acc[t], 0, 0, 0);
            }
        }
    }
    float bv[8];
    #pragma unroll
    for (int t = 0; t < 8; ++t) bv[t] = bias[t * 16 + (lane & 15)];
    #pragma unroll
    for (int r = 0; r < 4; ++r) {
        long row = r0 + (lane >> 4) * 4 + r;
        if (row >= NN) continue;
        float d = dinv[row];
        #pragma unroll
        for (int t = 0; t < 8; ++t) {
            float val = fmaxf(acc[t][r] + bv[t], 0.f);
            int col = t * 16 + (lane & 15);
            if (EPI == 0)
                ((unsigned char*)outp)[row * 128 + col] = (unsigned char)f2fp8(val * (16.0f * d));
            else
                ((unsigned short*)outp)[row * 128 + col] = f2bf(val);
        }
    }
}

// ---- segmented mean pool over bf16 h2: 4 waves per graph ----
__global__ __launch_bounds__(256) void k_poolmean(const unsigned* __restrict__ h,
        const int* __restrict__ seg_end, float* __restrict__ hg) {
    __shared__ float part[3][128];
    int g = blockIdx.x;
    int w = threadIdx.x >> 6, t = threadIdx.x & 63;
    int s = (g == 0) ? 0 : seg_end[g - 1];
    int e = seg_end[g];
    float a0 = 0.f, a1 = 0.f;
    for (int i = s + w; i < e; i += 4) {
        unsigned u = h[(long)i * 64 + t];
        a0 += __uint_as_float(u << 16);
        a1 += __uint_as_float(u & 0xffff0000u);
    }
    if (w) { part[w - 1][t * 2] = a0; part[w - 1][t * 2 + 1] = a1; }
    __syncthreads();
    if (w == 0) {
        a0 += part[0][t * 2] + part[1][t * 2] + part[2][t * 2];
        a1 += part[0][t * 2 + 1] + part[1][t * 2 + 1] + part[2][t * 2 + 1];
        float inv = (e > s) ? 1.0f / (float)(e - s) : 0.f;
        float2 o = { a0 * inv, a1 * inv };
        *(float2*)&hg[g * 128 + t * 2] = o;
    }
}

// ---- mu/logvar heads + reparameterise ----
__global__ __launch_bounds__(64) void k_head(const float* __restrict__ hg,
        const float* __restrict__ Wmu, const float* __restrict__ bmu,
        const float* __restrict__ Wlv, const float* __restrict__ blv,
        const float* __restrict__ eps, float* __restrict__ mu_o, float* __restrict__ lv_o,
        float* __restrict__ z) {
    __shared__ float row[128];
    int g = blockIdx.x, t = threadIdx.x;
    row[t]      = hg[g * 128 + t];
    row[t + 64] = hg[g * 128 + t + 64];
    __syncthreads();
    float mu = bmu[t], lv = blv[t];
    for (int k = 0; k < 128; ++k) {
        float rv = row[k];
        mu += rv * Wmu[k * 64 + t];
        lv += rv * Wlv[k * 64 + t];
    }
    mu_o[g * 64 + t] = mu;
    lv_o[g * 64 + t] = lv;
    z[g * 64 + t] = mu + eps[g * 64 + t] * expf(0.5f * lv);
}

// ---- small MLP layer ----
__global__ __launch_bounds__(128) void k_mlp(const float* __restrict__ A, int K,
        const float* __restrict__ W, const float* __restrict__ b, float* __restrict__ out) {
    __shared__ float row[128];
    int m = blockIdx.x, t = threadIdx.x;
    if (t < K) row[t] = A[m * K + t];
    __syncthreads();
    float acc = b[t];
    for (int k = 0; k < K; ++k) acc += row[k] * W[k * 128 + t];
    out[m * 128 + t] = fmaxf(acc, 0.f);
}

// ---- probs = sigmoid(A @ D3 + d3); 16-row m-tiles ----
__global__ __launch_bounds__(256) void k_dec3(const float* __restrict__ A,
        const float* __restrict__ W, const float* __restrict__ b, float* __restrict__ out) {
    __shared__ float alds[16][128];
    int m0 = blockIdx.y * 16;
    for (int i = threadIdx.x; i < 16 * 128; i += 256)
        alds[i >> 7][i & 127] = A[(m0 + (i >> 7)) * 128 + (i & 127)];
    __syncthreads();
    if (threadIdx.x >= 254) return;
    int c = blockIdx.x * 1016 + threadIdx.x * 4;
    float4 bb = *(const float4*)&b[c];
    float4 acc[16];
    #pragma unroll
    for (int r = 0; r < 16; ++r) acc[r] = bb;
    for (int k = 0; k < 128; ++k) {
        float4 w = *(const float4*)&W[(long)k * OUTS + c];
        #pragma unroll
        for (int r = 0; r < 16; ++r) {
            float a = alds[r][k];
            acc[r].x += a * w.x; acc[r].y += a * w.y;
            acc[r].z += a * w.z; acc[r].w += a * w.w;
        }
    }
    #pragma unroll
    for (int r = 0; r < 16; ++r) {
        float4 o;
        o.x = 1.f / (1.f + expf(-acc[r].x));
        o.y = 1.f / (1.f + expf(-acc[r].y));
        o.z = 1.f / (1.f + expf(-acc[r].z));
        o.w = 1.f / (1.f + expf(-acc[r].w));
        *(float4*)&out[(long)(m0 + r) * OUTS + c] = o;
    }
}

// ---- build symmetric adjacency ----
__global__ __launch_bounds__(256) void k_adj(const float* __restrict__ probs, float* __restrict__ adj) {
    int t = blockIdx.x * 256 + threadIdx.x;
    int g = t >> 12;
    int rem = t & 4095;
    int r = rem >> 5;
    int c0 = (rem & 31) * 4;
    const float* pg = &probs[g * OUTS];
    float4 o;
    float* op = (float*)&o;
    #pragma unroll
    for (int j = 0; j < 4; ++j) {
        int c = c0 + j;
        if (c == r) { op[j] = 0.f; continue; }
        int a = c < r ? c : r;
        int b = c < r ? r : c;
        int k = a * (255 - a) / 2 + (b - a - 1);
        op[j] = pg[k];
    }
    *(float4*)&adj[(long)t * 4] = o;
}

extern "C" void kernel_launch(void* const* d_in, const int* in_sizes, int n_in,
                              void* d_out, int out_size, void* d_ws, size_t ws_size,
                              hipStream_t stream) {
    const float* x   = (const float*)d_in[0];
    const int*   ei  = (const int*)d_in[1];
    const int* batch = (const int*)d_in[2];
    const float* eps = (const float*)d_in[3];
    const float* W1  = (const float*)d_in[4];
    const float* b1  = (const float*)d_in[5];
    const float* W2  = (const float*)d_in[6];
    const float* b2  = (const float*)d_in[7];
    const float* Wmu = (const float*)d_in[8];
    const float* bmu = (const float*)d_in[9];
    const float* Wlv = (const float*)d_in[10];
    const float* blv = (const float*)d_in[11];
    const float* D1  = (const float*)d_in[12];
    const float* d1  = (const float*)d_in[13];
    const float* D2  = (const float*)d_in[14];
    const float* d2  = (const float*)d_in[15];
    const float* D3  = (const float*)d_in[16];
    const float* d3  = (const float*)d_in[17];

    const int* esrc = ei;
    const int* edst = ei + NE;

    float* out  = (float*)d_out;
    float* mu_o = out + 8388608;
    float* lv_o = mu_o + 32768;

    // --- CSR + small scratch in d_out (region fully overwritten by k_adj at the end) ---
    int*   colidx   = (int*)out;                 // 1,600,000
    int*   cnti     = colidx + 1600000;          // 100,000
    int*   rowptr   = cnti + 100000;             // 100,000
    int*   seg_end  = rowptr + 100000;           // 512
    float* dinv     = (float*)(seg_end + 512);   // 100,000
    int*   scanhist = (int*)(dinv + 100000);     // 196*197 = 38,612
    int*   bucketbase = scanhist + 38612;        // 196  (ends ~1.94M << 8.39M)

    // --- ws layout (float-unit offsets) ---
    float* ws = (float*)d_ws;
    unsigned* u1u = (unsigned*)ws;                         // 3.2M uints (f16x2)
    unsigned* s1u = u1u + 3200000;                         // 3.2M uints (f16x2)
    unsigned char* u2b = (unsigned char*)(ws + 6400000);   // 12.8M bytes (fp8)
    unsigned* s2u = (unsigned*)(ws + 9600000);             // 6.4M uints (bf16x2)
    unsigned* h2b = (unsigned*)(ws + 16000000);            // 6.4M uints (bf16x2)
    unsigned short* wt1 = (unsigned short*)(ws + 22400000);   // 8192 u16 (f16)
    unsigned short* wt2 = wt1 + 8192;                         // 16384 u16 (bf16)
    int* tmp = (int*)(ws + 22420000);                      // 1.6M+ ints
    // decoder scratch aliases u1/s1 (dead after gemm1)
    float* hg    = ws;
    float* zbuf  = hg + 65536;
    float* p1    = zbuf + 32768;
    float* p2    = p1 + 65536;
    float* probs = p2 + 65536;

    // ---- CSR build: zero global atomics ----
    k_part<<<NPB, 256, 0, stream>>>(esrc, edst, tmp, scanhist);
    k_btot<<<1, 256, 0, stream>>>(scanhist, bucketbase);
    k_fill2<<<NB2, 256, 0, stream>>>(bucketbase, scanhist, tmp, colidx, cnti, rowptr, dinv);
    k_segend<<<(NN + 255) / 256, 256, 0, stream>>>(batch, seg_end);

    // ---- weights: wt1 f16, wt2 bf16 (transposed) ----
    k_wt<64, 1><<<32, 256, 0, stream>>>(W1, wt1);
    k_wt<128, 0><<<64, 256, 0, stream>>>(W2, wt2);

    // ---- conv1 (f16 gather in 64-ch x-space, then f16 MFMA GEMM -> fp8) ----
    k_scale_x<<<12500, 256, 0, stream>>>(x, dinv, u1u);
    k_gather1<<<12500, 256, 0, stream>>>(rowptr, cnti, colidx, u1u, dinv, s1u);
    k_gemm_mfma<64, 0, 1><<<1563, 256, 0, stream>>>((const unsigned short*)s1u, wt1, dinv, b1, u2b);

    // ---- conv2 (fp8 packed-decode gather, then bf16 MFMA GEMM) ----
    k_gather2<<<12500, 256, 0, stream>>>(rowptr, cnti, colidx, (const unsigned*)u2b, dinv, s2u);
    k_gemm_mfma<128, 1, 0><<<1563, 256, 0, stream>>>((const unsigned short*)s2u, wt2, dinv, b2, h2b);

    // ---- pool + heads ----
    k_poolmean<<<NG, 256, 0, stream>>>(h2b, seg_end, hg);
    k_head<<<NG, 64, 0, stream>>>(hg, Wmu, bmu, Wlv, blv, eps, mu_o, lv_o, zbuf);

    // ---- decoder ----
    k_mlp<<<NG, 128, 0, stream>>>(zbuf, 64, D1, d1, p1);
    k_mlp<<<NG, 128, 0, stream>>>(p1, 128, D2, d2, p2);
    dim3 g3(8, 32);
    k_dec3<<<g3, 256, 0, stream>>>(p2, D3, d3, probs);
    k_adj<<<8192, 256, 0, stream>>>(probs, out);
}

// Round 9
// 290.105 us; speedup vs baseline: 2.6409x; 1.1394x over previous
//
#include <hip/hip_runtime.h>
#include <hip/hip_fp16.h>

#define NN 100000
#define NE 1600000
#define NG 512
#define OUTS 8128
#define NB2 196     // coarse buckets of 512 nodes (196*512 = 100352 >= NN)
#define CHUNK 8192
#define NPB 196     // ceil(NE/CHUNK)

typedef short bf16x8 __attribute__((ext_vector_type(8)));
typedef _Float16 f16x8 __attribute__((ext_vector_type(8)));
typedef _Float16 f16x2 __attribute__((ext_vector_type(2)));
typedef float f32x4 __attribute__((ext_vector_type(4)));

__device__ __forceinline__ unsigned pack_bf16x2(float a, float b) {
    unsigned ua = __float_as_uint(a);
    unsigned ub = __float_as_uint(b);
    ua = (ua + 0x7fffu + ((ua >> 16) & 1u)) >> 16;
    ub = (ub + 0x7fffu + ((ub >> 16) & 1u)) >> 16;
    return ua | (ub << 16);
}
__device__ __forceinline__ unsigned short f2bf(float f) {
    unsigned u = __float_as_uint(f);
    u = (u + 0x7fffu + ((u >> 16) & 1u)) >> 16;
    return (unsigned short)u;
}
// f32 pair -> packed f16x2 (RTZ), as raw uint
__device__ __forceinline__ unsigned cvt_pkrtz_u(float a, float b) {
    auto h = __builtin_amdgcn_cvt_pkrtz(a, b);
    union { decltype(h) h2; unsigned u; } c; c.h2 = h; return c.u;
}
__device__ __forceinline__ f16x2 u2h(unsigned u) { union { unsigned u; f16x2 h; } c; c.u = u; return c.h; }

// e4m3 encode for f >= 0 (relu'd): e4m3(v) == f16(v/256) with 10->3 mantissa round
__device__ __forceinline__ unsigned f2fp8(float f) {
    unsigned h = (unsigned)__half_as_ushort(__float2half(f * 0.00390625f));
    return (h + 0x3Fu + ((h >> 7) & 1u)) >> 7;
}

// ---- phase 1: per-block partition of an 8192-edge chunk into 196 coarse buckets ----
__global__ __launch_bounds__(256) void k_part(const int* __restrict__ src, const int* __restrict__ dst,
        int* __restrict__ tmp, int* __restrict__ scanhist) {
    __shared__ int hist[NB2], cur[NB2], scan[256];
    int p = blockIdx.x, t = threadIdx.x;
    int e0 = p * CHUNK;
    int e1 = min(e0 + CHUNK, NE);
    for (int i = t; i < NB2; i += 256) hist[i] = 0;
    __syncthreads();
    for (int e = e0 + t; e < e1; e += 256)
        atomicAdd(&hist[dst[e] >> 9], 1);
    __syncthreads();
    int h = (t < NB2) ? hist[t] : 0;
    scan[t] = h;
    __syncthreads();
    for (int off = 1; off < 256; off <<= 1) {
        int v = (t >= off) ? scan[t - off] : 0;
        __syncthreads();
        scan[t] += v;
        __syncthreads();
    }
    if (t < NB2) {
        int excl = scan[t] - h;
        cur[t] = excl;
        scanhist[p * (NB2 + 1) + t] = excl;
    }
    if (t == 0) scanhist[p * (NB2 + 1) + NB2] = e1 - e0;
    __syncthreads();
    for (int e = e0 + t; e < e1; e += 256) {
        int d = dst[e];
        int b = d >> 9;
        int r = atomicAdd(&cur[b], 1);          // LDS atomic only
        tmp[e0 + r] = (src[e] << 9) | (d & 511);
    }
}

// ---- bucket totals + exclusive scan -> bucketbase (1 block) ----
__global__ __launch_bounds__(256) void k_btot(const int* __restrict__ scanhist, int* __restrict__ bucketbase) {
    __shared__ int sc[256];
    int b = threadIdx.x;
    int tot = 0;
    if (b < NB2) {
        for (int p = 0; p < NPB; ++p)
            tot += scanhist[p * (NB2 + 1) + b + 1] - scanhist[p * (NB2 + 1) + b];
    }
    sc[b] = tot;
    __syncthreads();
    for (int off = 1; off < 256; off <<= 1) {
        int v = (b >= off) ? sc[b - off] : 0;
        __syncthreads();
        sc[b] += v;
        __syncthreads();
    }
    if (b < NB2) bucketbase[b] = sc[b] - tot;
}

// ---- phase 2: per-bucket count + scan + place; emits cnti/rowptr/dinv/colidx ----
__global__ __launch_bounds__(256) void k_fill2(const int* __restrict__ bucketbase,
        const int* __restrict__ scanhist, const int* __restrict__ tmp,
        int* __restrict__ colidx, int* __restrict__ cnti, int* __restrict__ rowptr,
        float* __restrict__ dinv) {
    __shared__ int lc[512], rb[512], sc[256];
    int b = blockIdx.x, t = threadIdx.x;
    int n0 = b << 9;
    lc[t] = 0; lc[t + 256] = 0;
    __syncthreads();
    int w = t >> 6, lane = t & 63;
    // count phase
    for (int p = w; p < NPB; p += 4) {
        int s0 = scanhist[p * (NB2 + 1) + b];
        int s1 = scanhist[p * (NB2 + 1) + b + 1];
        int base = p * CHUNK;
        for (int i = s0 + lane; i < s1; i += 64)
            atomicAdd(&lc[tmp[base + i] & 511], 1);
    }
    __syncthreads();
    // scan 512 via 256 pair-partials
    int v0 = lc[2 * t], v1 = lc[2 * t + 1];
    int s = v0 + v1;
    sc[t] = s;
    __syncthreads();
    for (int off = 1; off < 256; off <<= 1) {
        int v = (t >= off) ? sc[t - off] : 0;
        __syncthreads();
        sc[t] += v;
        __syncthreads();
    }
    int excl = sc[t] - s;
    int base0 = bucketbase[b];
    rb[2 * t] = base0 + excl;
    rb[2 * t + 1] = base0 + excl + v0;
    int node0 = n0 + 2 * t;
    if (node0 < NN) {
        cnti[node0] = v0;
        rowptr[node0] = base0 + excl;
        dinv[node0] = rsqrtf((float)v0 + 1.0f);
    }
    if (node0 + 1 < NN) {
        cnti[node0 + 1] = v1;
        rowptr[node0 + 1] = base0 + excl + v0;
        dinv[node0 + 1] = rsqrtf((float)v1 + 1.0f);
    }
    lc[2 * t] = 0; lc[2 * t + 1] = 0;
    __syncthreads();
    // place phase
    for (int p = w; p < NPB; p += 4) {
        int s0 = scanhist[p * (NB2 + 1) + b];
        int s1 = scanhist[p * (NB2 + 1) + b + 1];
        int base = p * CHUNK;
        for (int i = s0 + lane; i < s1; i += 64) {
            int v = tmp[base + i];
            int dl = v & 511;
            int pos = atomicAdd(&lc[dl], 1);    // LDS atomic only
            colidx[rb[dl] + pos] = v >> 9;
        }
    }
}

// ---- segment ends from sorted batch ----
__global__ __launch_bounds__(256) void k_segend(const int* __restrict__ batch, int* __restrict__ seg_end) {
    int i = blockIdx.x * 256 + threadIdx.x;
    if (i >= NN) return;
    int b = batch[i];
    int bn = (i == NN - 1) ? NG : batch[i + 1];
    for (int g = b; g < bn; ++g) seg_end[g] = i + 1;
    if (i == 0) {
        for (int g = 0; g < b; ++g) seg_end[g] = 0;
    }
}

// ---- W[K][128] fp32 -> WT[128][K]; F16=1 -> f16 bits, else bf16 ----
template<int K, int F16>
__global__ __launch_bounds__(256) void k_wt(const float* __restrict__ W, unsigned short* __restrict__ wt) {
    int e = blockIdx.x * 256 + threadIdx.x;
    int n = e / K, k = e - n * K;
    float v = W[k * 128 + n];
    wt[e] = F16 ? (unsigned short)__half_as_ushort(__float2half(v)) : f2bf(v);
}

// ---- u1 = f16(x * dinv[row]), 64ch ----
__global__ __launch_bounds__(256) void k_scale_x(const float* __restrict__ x,
        const float* __restrict__ dinv, unsigned* __restrict__ u1) {
    int i = blockIdx.x * 256 + threadIdx.x;   // < NN*32
    int row = i >> 5, c = i & 31;
    float2 v = *(const float2*)&x[(long)row * 64 + c * 2];
    float d = dinv[row];
    u1[i] = cvt_pkrtz_u(v.x * d, v.y * d);
}

// ---- gather1: s1 = f16(dinv_n * (u1[n] + sum u1[src])), 64ch f16 ----
// 16 lanes/node, uint2 (4ch) per lane, 4-deep neighbor unroll (32B in flight/lane)
__global__ __launch_bounds__(256) void k_gather1(const int* __restrict__ rowptr,
        const int* __restrict__ cnti, const int* __restrict__ colidx,
        const unsigned* __restrict__ u, const float* __restrict__ dinv,
        unsigned* __restrict__ s1) {
    int node = blockIdx.x * 16 + (threadIdx.x >> 4);
    int lane = threadIdx.x & 15;
    const uint2* uf = (const uint2*)u;          // row = 16 uint2
    uint2 self = uf[node * 16 + lane];
    f16x2 a0 = u2h(self.x), a1 = u2h(self.y);
    f16x2 b0 = {(_Float16)0.f, (_Float16)0.f}, b1 = b0;
    f16x2 c0 = b0, c1 = b0, d0 = b0, d1 = b0;
    int n = cnti[node];
    const int* ci = colidx + rowptr[node];
    int j = 0;
    for (; j + 4 <= n; j += 4) {
        uint2 va = uf[ci[j] * 16 + lane];
        uint2 vb = uf[ci[j + 1] * 16 + lane];
        uint2 vc = uf[ci[j + 2] * 16 + lane];
        uint2 vd = uf[ci[j + 3] * 16 + lane];
        a0 += u2h(va.x); a1 += u2h(va.y);
        b0 += u2h(vb.x); b1 += u2h(vb.y);
        c0 += u2h(vc.x); c1 += u2h(vc.y);
        d0 += u2h(vd.x); d1 += u2h(vd.y);
    }
    for (; j < n; ++j) {
        uint2 va = uf[ci[j] * 16 + lane];
        a0 += u2h(va.x); a1 += u2h(va.y);
    }
    a0 += b0 + c0 + d0;
    a1 += b1 + c1 + d1;
    float d = dinv[node];
    uint2 o;
    o.x = cvt_pkrtz_u((float)a0[0] * d, (float)a0[1] * d);
    o.y = cvt_pkrtz_u((float)a1[0] * d, (float)a1[1] * d);
    *(uint2*)&s1[node * 32 + lane * 2] = o;
}

// ---- gather2: s2 = bf16(16*dinv_n * sum fp8rows), 128ch fp8 ----
// 16 lanes/node, uint2 (8ch) per lane, 4-deep unroll, sign-free packed decode
__global__ __launch_bounds__(256) void k_gather2(const int* __restrict__ rowptr,
        const int* __restrict__ cnti, const int* __restrict__ colidx,
        const unsigned* __restrict__ u, const float* __restrict__ dinv,
        unsigned* __restrict__ s2) {
    int node = blockIdx.x * 16 + (threadIdx.x >> 4);
    int lane = threadIdx.x & 15;
    const uint2* uf = (const uint2*)u;          // row = 16 uint2 (128 fp8)
    uint2 self = uf[node * 16 + lane];
    f16x2 xa = u2h((self.x & 0x007f007fu) << 7);   // c0,c2
    f16x2 xb = u2h((self.x & 0x7f007f00u) >> 1);   // c1,c3
    f16x2 ya = u2h((self.y & 0x007f007fu) << 7);   // c4,c6
    f16x2 yb = u2h((self.y & 0x7f007f00u) >> 1);   // c5,c7
    f16x2 z = {(_Float16)0.f, (_Float16)0.f};
    f16x2 xa2 = z, xb2 = z, ya2 = z, yb2 = z;
    int n = cnti[node];
    const int* ci = colidx + rowptr[node];
    int j = 0;
    for (; j + 4 <= n; j += 4) {
        uint2 va = uf[ci[j] * 16 + lane];
        uint2 vb = uf[ci[j + 1] * 16 + lane];
        uint2 vc = uf[ci[j + 2] * 16 + lane];
        uint2 vd = uf[ci[j + 3] * 16 + lane];
        xa  += u2h((va.x & 0x007f007fu) << 7);  xb  += u2h((va.x & 0x7f007f00u) >> 1);
        ya  += u2h((va.y & 0x007f007fu) << 7);  yb  += u2h((va.y & 0x7f007f00u) >> 1);
        xa2 += u2h((vb.x & 0x007f007fu) << 7);  xb2 += u2h((vb.x & 0x7f007f00u) >> 1);
        ya2 += u2h((vb.y & 0x007f007fu) << 7);  yb2 += u2h((vb.y & 0x7f007f00u) >> 1);
        xa  += u2h((vc.x & 0x007f007fu) << 7);  xb  += u2h((vc.x & 0x7f007f00u) >> 1);
        ya  += u2h((vc.y & 0x007f007fu) << 7);  yb  += u2h((vc.y & 0x7f007f00u) >> 1);
        xa2 += u2h((vd.x & 0x007f007fu) << 7);  xb2 += u2h((vd.x & 0x7f007f00u) >> 1);
        ya2 += u2h((vd.y & 0x007f007fu) << 7);  yb2 += u2h((vd.y & 0x7f007f00u) >> 1);
    }
    for (; j < n; ++j) {
        uint2 va = uf[ci[j] * 16 + lane];
        xa += u2h((va.x & 0x007f007fu) << 7);  xb += u2h((va.x & 0x7f007f00u) >> 1);
        ya += u2h((va.y & 0x007f007fu) << 7);  yb += u2h((va.y & 0x7f007f00u) >> 1);
    }
    xa += xa2; xb += xb2; ya += ya2; yb += yb2;
    float d = dinv[node] * 16.0f;   // *256 (decode) / 16 (encode scale)
    uint4 o;
    o.x = pack_bf16x2((float)xa[0] * d, (float)xb[0] * d);   // c0,c1
    o.y = pack_bf16x2((float)xa[1] * d, (float)xb[1] * d);   // c2,c3
    o.z = pack_bf16x2((float)ya[0] * d, (float)yb[0] * d);   // c4,c5
    o.w = pack_bf16x2((float)ya[1] * d, (float)yb[1] * d);   // c6,c7
    *(uint4*)&s2[node * 64 + lane * 4] = o;
}

// ---- MFMA GEMM: h = relu(A@W + bias); AF16: f16 inputs; EPI 0: out fp8(16*dinv*h); 1: bf16 ----
template<int K, int EPI, int AF16>
__global__ __launch_bounds__(256) void k_gemm_mfma(const unsigned short* __restrict__ Ab,
        const unsigned short* __restrict__ wt, const float* __restrict__ dinv,
        const float* __restrict__ bias, void* __restrict__ outp) {
    constexpr int KS = K / 32;
    constexpr int SLOTS = K / 8;
    __shared__ __align__(16) unsigned short wlds[128 * K];
    char* lb = (char*)wlds;
    for (int c = threadIdx.x; c < 128 * SLOTS; c += 256) {
        int n = c / SLOTS, s = c - n * SLOTS;
        *(uint4*)(lb + n * (2 * K) + ((s ^ (n & 7)) << 4)) = *(const uint4*)(wt + c * 8);
    }
    __syncthreads();
    int lane = threadIdx.x & 63;
    int w = threadIdx.x >> 6;
    int r0 = blockIdx.x * 64 + w * 16;
    int arow = r0 + (lane & 15);
    if (arow >= NN) arow = NN - 1;
    bf16x8 af[KS];
    #pragma unroll
    for (int ks = 0; ks < KS; ++ks)
        af[ks] = *(const bf16x8*)&Ab[(long)arow * K + ks * 32 + (lane >> 4) * 8];
    f32x4 acc[8];
    #pragma unroll
    for (int t = 0; t < 8; ++t) acc[t] = (f32x4){0.f, 0.f, 0.f, 0.f};
    #pragma unroll
    for (int ks = 0; ks < KS; ++ks) {
        #pragma unroll
        for (int t = 0; t < 8; ++t) {
            int n = t * 16 + (lane & 15);
            int slot = ks * 4 + (lane >> 4);
            bf16x8 braw = *(const bf16x8*)(lb + n * (2 * K) + ((slot ^ (n & 7)) << 4));
            if constexpr (AF16) {
                union { bf16x8 r; f16x8 h; } ca, cb;
                ca.r = af[ks]; cb.r = braw;
                acc[t] = __builtin_amdgcn_mfma_f32_16x16x32_f16(ca.h, cb.h, acc[t], 0, 0, 0);
            } else {
                acc[t] = __builtin_amdgcn_mfma_f32_16x16x32_bf16(af[ks], braw, acc[t], 0, 0, 0);
            }
        }
    }
    float bv[8];
    #pragma unroll
    for (int t = 0; t < 8; ++t) bv[t] = bias[t * 16 + (lane & 15)];
    #pragma unroll
    for (int r = 0; r < 4; ++r) {
        long row = r0 + (lane >> 4) * 4 + r;
        if (row >= NN) continue;
        float d = dinv[row];
        #pragma unroll
        for (int t = 0; t < 8; ++t) {
            float val = fmaxf(acc[t][r] + bv[t], 0.f);
            int col = t * 16 + (lane & 15);
            if (EPI == 0)
                ((unsigned char*)outp)[row * 128 + col] = (unsigned char)f2fp8(val * (16.0f * d));
            else
                ((unsigned short*)outp)[row * 128 + col] = f2bf(val);
        }
    }
}

// ---- segmented mean pool over bf16 h2: 4 waves per graph ----
__global__ __launch_bounds__(256) void k_poolmean(const unsigned* __restrict__ h,
        const int* __restrict__ seg_end, float* __restrict__ hg) {
    __shared__ float part[3][128];
    int g = blockIdx.x;
    int w = threadIdx.x >> 6, t = threadIdx.x & 63;
    int s = (g == 0) ? 0 : seg_end[g - 1];
    int e = seg_end[g];
    float a0 = 0.f, a1 = 0.f;
    for (int i = s + w; i < e; i += 4) {
        unsigned u = h[(long)i * 64 + t];
        a0 += __uint_as_float(u << 16);
        a1 += __uint_as_float(u & 0xffff0000u);
    }
    if (w) { part[w - 1][t * 2] = a0; part[w - 1][t * 2 + 1] = a1; }
    __syncthreads();
    if (w == 0) {
        a0 += part[0][t * 2] + part[1][t * 2] + part[2][t * 2];
        a1 += part[0][t * 2 + 1] + part[1][t * 2 + 1] + part[2][t * 2 + 1];
        float inv = (e > s) ? 1.0f / (float)(e - s) : 0.f;
        float2 o = { a0 * inv, a1 * inv };
        *(float2*)&hg[g * 128 + t * 2] = o;
    }
}

// ---- mu/logvar heads + reparameterise ----
__global__ __launch_bounds__(64) void k_head(const float* __restrict__ hg,
        const float* __restrict__ Wmu, const float* __restrict__ bmu,
        const float* __restrict__ Wlv, const float* __restrict__ blv,
        const float* __restrict__ eps, float* __restrict__ mu_o, float* __restrict__ lv_o,
        float* __restrict__ z) {
    __shared__ float row[128];
    int g = blockIdx.x, t = threadIdx.x;
    row[t]      = hg[g * 128 + t];
    row[t + 64] = hg[g * 128 + t + 64];
    __syncthreads();
    float mu = bmu[t], lv = blv[t];
    for (int k = 0; k < 128; ++k) {
        float rv = row[k];
        mu += rv * Wmu[k * 64 + t];
        lv += rv * Wlv[k * 64 + t];
    }
    mu_o[g * 64 + t] = mu;
    lv_o[g * 64 + t] = lv;
    z[g * 64 + t] = mu + eps[g * 64 + t] * expf(0.5f * lv);
}

// ---- small MLP layer ----
__global__ __launch_bounds__(128) void k_mlp(const float* __restrict__ A, int K,
        const float* __restrict__ W, const float* __restrict__ b, float* __restrict__ out) {
    __shared__ float row[128];
    int m = blockIdx.x, t = threadIdx.x;
    if (t < K) row[t] = A[m * K + t];
    __syncthreads();
    float acc = b[t];
    for (int k = 0; k < K; ++k) acc += row[k] * W[k * 128 + t];
    out[m * 128 + t] = fmaxf(acc, 0.f);
}

// ---- probs = sigmoid(A @ D3 + d3); 16-row m-tiles ----
__global__ __launch_bounds__(256) void k_dec3(const float* __restrict__ A,
        const float* __restrict__ W, const float* __restrict__ b, float* __restrict__ out) {
    __shared__ float alds[16][128];
    int m0 = blockIdx.y * 16;
    for (int i = threadIdx.x; i < 16 * 128; i += 256)
        alds[i >> 7][i & 127] = A[(m0 + (i >> 7)) * 128 + (i & 127)];
    __syncthreads();
    if (threadIdx.x >= 254) return;
    int c = blockIdx.x * 1016 + threadIdx.x * 4;
    float4 bb = *(const float4*)&b[c];
    float4 acc[16];
    #pragma unroll
    for (int r = 0; r < 16; ++r) acc[r] = bb;
    for (int k = 0; k < 128; ++k) {
        float4 w = *(const float4*)&W[(long)k * OUTS + c];
        #pragma unroll
        for (int r = 0; r < 16; ++r) {
            float a = alds[r][k];
            acc[r].x += a * w.x; acc[r].y += a * w.y;
            acc[r].z += a * w.z; acc[r].w += a * w.w;
        }
    }
    #pragma unroll
    for (int r = 0; r < 16; ++r) {
        float4 o;
        o.x = 1.f / (1.f + expf(-acc[r].x));
        o.y = 1.f / (1.f + expf(-acc[r].y));
        o.z = 1.f / (1.f + expf(-acc[r].z));
        o.w = 1.f / (1.f + expf(-acc[r].w));
        *(float4*)&out[(long)(m0 + r) * OUTS + c] = o;
    }
}

// ---- build symmetric adjacency ----
__global__ __launch_bounds__(256) void k_adj(const float* __restrict__ probs, float* __restrict__ adj) {
    int t = blockIdx.x * 256 + threadIdx.x;
    int g = t >> 12;
    int rem = t & 4095;
    int r = rem >> 5;
    int c0 = (rem & 31) * 4;
    const float* pg = &probs[g * OUTS];
    float4 o;
    float* op = (float*)&o;
    #pragma unroll
    for (int j = 0; j < 4; ++j) {
        int c = c0 + j;
        if (c == r) { op[j] = 0.f; continue; }
        int a = c < r ? c : r;
        int b = c < r ? r : c;
        int k = a * (255 - a) / 2 + (b - a - 1);
        op[j] = pg[k];
    }
    *(float4*)&adj[(long)t * 4] = o;
}

extern "C" void kernel_launch(void* const* d_in, const int* in_sizes, int n_in,
                              void* d_out, int out_size, void* d_ws, size_t ws_size,
                              hipStream_t stream) {
    const float* x   = (const float*)d_in[0];
    const int*   ei  = (const int*)d_in[1];
    const int* batch = (const int*)d_in[2];
    const float* eps = (const float*)d_in[3];
    const float* W1  = (const float*)d_in[4];
    const float* b1  = (const float*)d_in[5];
    const float* W2  = (const float*)d_in[6];
    const float* b2  = (const float*)d_in[7];
    const float* Wmu = (const float*)d_in[8];
    const float* bmu = (const float*)d_in[9];
    const float* Wlv = (const float*)d_in[10];
    const float* blv = (const float*)d_in[11];
    const float* D1  = (const float*)d_in[12];
    const float* d1  = (const float*)d_in[13];
    const float* D2  = (const float*)d_in[14];
    const float* d2  = (const float*)d_in[15];
    const float* D3  = (const float*)d_in[16];
    const float* d3  = (const float*)d_in[17];

    const int* esrc = ei;
    const int* edst = ei + NE;

    float* out  = (float*)d_out;
    float* mu_o = out + 8388608;
    float* lv_o = mu_o + 32768;

    // --- CSR + small scratch in d_out (region fully overwritten by k_adj at the end) ---
    int*   colidx   = (int*)out;                 // 1,600,000
    int*   cnti     = colidx + 1600000;          // 100,000
    int*   rowptr   = cnti + 100000;             // 100,000
    int*   seg_end  = rowptr + 100000;           // 512
    float* dinv     = (float*)(seg_end + 512);   // 100,000
    int*   scanhist = (int*)(dinv + 100000);     // 196*197 = 38,612
    int*   bucketbase = scanhist + 38612;        // 196  (ends ~1.94M << 8.39M)

    // --- ws layout (float-unit offsets) ---
    float* ws = (float*)d_ws;
    unsigned* u1u = (unsigned*)ws;                         // 3.2M uints (f16x2)
    unsigned* s1u = u1u + 3200000;                         // 3.2M uints (f16x2)
    unsigned char* u2b = (unsigned char*)(ws + 6400000);   // 12.8M bytes (fp8)
    unsigned* s2u = (unsigned*)(ws + 9600000);             // 6.4M uints (bf16x2)
    unsigned* h2b = (unsigned*)(ws + 16000000);            // 6.4M uints (bf16x2)
    unsigned short* wt1 = (unsigned short*)(ws + 22400000);   // 8192 u16 (f16)
    unsigned short* wt2 = wt1 + 8192;                         // 16384 u16 (bf16)
    int* tmp = (int*)(ws + 22420000);                      // 1.6M+ ints
    // decoder scratch aliases u1/s1 (dead after gemm1)
    float* hg    = ws;
    float* zbuf  = hg + 65536;
    float* p1    = zbuf + 32768;
    float* p2    = p1 + 65536;
    float* probs = p2 + 65536;

    // ---- CSR build: zero global atomics ----
    k_part<<<NPB, 256, 0, stream>>>(esrc, edst, tmp, scanhist);
    k_btot<<<1, 256, 0, stream>>>(scanhist, bucketbase);
    k_fill2<<<NB2, 256, 0, stream>>>(bucketbase, scanhist, tmp, colidx, cnti, rowptr, dinv);
    k_segend<<<(NN + 255) / 256, 256, 0, stream>>>(batch, seg_end);

    // ---- weights: wt1 f16, wt2 bf16 (transposed) ----
    k_wt<64, 1><<<32, 256, 0, stream>>>(W1, wt1);
    k_wt<128, 0><<<64, 256, 0, stream>>>(W2, wt2);

    // ---- conv1 (f16 gather in 64-ch x-space, then f16 MFMA GEMM -> fp8) ----
    k_scale_x<<<12500, 256, 0, stream>>>(x, dinv, u1u);
    k_gather1<<<6250, 256, 0, stream>>>(rowptr, cnti, colidx, u1u, dinv, s1u);
    k_gemm_mfma<64, 0, 1><<<1563, 256, 0, stream>>>((const unsigned short*)s1u, wt1, dinv, b1, u2b);

    // ---- conv2 (fp8 packed-decode gather, then bf16 MFMA GEMM) ----
    k_gather2<<<6250, 256, 0, stream>>>(rowptr, cnti, colidx, (const unsigned*)u2b, dinv, s2u);
    k_gemm_mfma<128, 1, 0><<<1563, 256, 0, stream>>>((const unsigned short*)s2u, wt2, dinv, b2, h2b);

    // ---- pool + heads ----
    k_poolmean<<<NG, 256, 0, stream>>>(h2b, seg_end, hg);
    k_head<<<NG, 64, 0, stream>>>(hg, Wmu, bmu, Wlv, blv, eps, mu_o, lv_o, zbuf);

    // ---- decoder ----
    k_mlp<<<NG, 128, 0, stream>>>(zbuf, 64, D1, d1, p1);
    k_mlp<<<NG, 128, 0, stream>>>(p1, 128, D2, d2, p2);
    dim3 g3(8, 32);
    k_dec3<<<g3, 256, 0, stream>>>(p2, D3, d3, probs);
    k_adj<<<8192, 256, 0, stream>>>(probs, out);
}